// Round 8
// baseline (677.435 us; speedup 1.0000x reference)
//
#include <hip/hip_runtime.h>
#include <math.h>

#define NN 100000
#define EE 800000
#define ETOT (EE + NN)
// HID=64, HEADS=4, OBS=128, ACT=32

// ---------------- GEMM: C[M,Nc] = A[M,K] @ B[K,Nc] (+bias, optional relu) ----------------
// BM=128, BN=64 (gy=1 -> A fetched once), BK=32, double-buffered LDS, 8x4 micro-tile.
// K must be a multiple of 32 (all call sites: 64/128/256). Nc <= 64.
__global__ __launch_bounds__(256) void gemm_kernel(
    const float* __restrict__ A, const float* __restrict__ B,
    const float* __restrict__ bias, float* __restrict__ C,
    int M, int K, int Nc, int doRelu)
{
    __shared__ __align__(16) float sA[2][32 * 132];  // [k][row 0..127], stride 132
    __shared__ __align__(16) float sB[2][32 * 68];   // [k][col 0..63],  stride 68

    const int bm = blockIdx.x * 128;
    const int tid = threadIdx.x;
    const int ty = tid >> 4;        // 0..15  -> rows ty*4+i and 64+ty*4+i
    const int tx = tid & 15;        // 0..15  -> cols tx*4+j

    const int ar = tid >> 3;        // 0..31  A-stage row base
    const int ac = (tid & 7) * 4;   // 0..28  A-stage k offset (float4)
    const int brow = tid >> 4;      // 0..15  B-stage row base
    const int bcol = (tid & 15) * 4;// 0..60  B-stage col (float4)

    float acc[8][4] = {};
    float4 ra[4], rb[2];
    const int NT = K >> 5;

    // ---- prologue: stage tile 0 ----
#pragma unroll
    for (int j = 0; j < 4; ++j) {
        int gr = bm + ar + 32 * j;
        ra[j] = make_float4(0.f, 0.f, 0.f, 0.f);
        if (gr < M) ra[j] = *(const float4*)&A[(size_t)gr * K + ac];
    }
#pragma unroll
    for (int j = 0; j < 2; ++j) {
        rb[j] = make_float4(0.f, 0.f, 0.f, 0.f);
        if (bcol < Nc) rb[j] = *(const float4*)&B[(size_t)(brow + 16 * j) * Nc + bcol];
    }
#pragma unroll
    for (int j = 0; j < 4; ++j) {
        int row = ar + 32 * j;
        sA[0][(ac + 0) * 132 + row] = ra[j].x;
        sA[0][(ac + 1) * 132 + row] = ra[j].y;
        sA[0][(ac + 2) * 132 + row] = ra[j].z;
        sA[0][(ac + 3) * 132 + row] = ra[j].w;
    }
#pragma unroll
    for (int j = 0; j < 2; ++j)
        *(float4*)&sB[0][(brow + 16 * j) * 68 + bcol] = rb[j];
    __syncthreads();

    for (int t = 0; t < NT; ++t) {
        const int cur = t & 1;
        // issue next-tile global loads before compute (latency hides under FMAs)
        if (t + 1 < NT) {
            const int k0 = (t + 1) << 5;
#pragma unroll
            for (int j = 0; j < 4; ++j) {
                int gr = bm + ar + 32 * j;
                ra[j] = make_float4(0.f, 0.f, 0.f, 0.f);
                if (gr < M) ra[j] = *(const float4*)&A[(size_t)gr * K + k0 + ac];
            }
#pragma unroll
            for (int j = 0; j < 2; ++j) {
                rb[j] = make_float4(0.f, 0.f, 0.f, 0.f);
                if (bcol < Nc) rb[j] = *(const float4*)&B[(size_t)(k0 + brow + 16 * j) * Nc + bcol];
            }
        }
#pragma unroll
        for (int k = 0; k < 32; ++k) {
            float4 a0 = *(const float4*)&sA[cur][k * 132 + ty * 4];
            float4 a1 = *(const float4*)&sA[cur][k * 132 + 64 + ty * 4];
            float4 b0 = *(const float4*)&sB[cur][k * 68 + tx * 4];
            float a[8] = {a0.x, a0.y, a0.z, a0.w, a1.x, a1.y, a1.z, a1.w};
            float b[4] = {b0.x, b0.y, b0.z, b0.w};
#pragma unroll
            for (int i = 0; i < 8; ++i)
#pragma unroll
                for (int j2 = 0; j2 < 4; ++j2)
                    acc[i][j2] = fmaf(a[i], b[j2], acc[i][j2]);
        }
        __syncthreads();
        if (t + 1 < NT) {
            const int nxt = cur ^ 1;
#pragma unroll
            for (int j = 0; j < 4; ++j) {
                int row = ar + 32 * j;
                sA[nxt][(ac + 0) * 132 + row] = ra[j].x;
                sA[nxt][(ac + 1) * 132 + row] = ra[j].y;
                sA[nxt][(ac + 2) * 132 + row] = ra[j].z;
                sA[nxt][(ac + 3) * 132 + row] = ra[j].w;
            }
#pragma unroll
            for (int j = 0; j < 2; ++j)
                *(float4*)&sB[nxt][(brow + 16 * j) * 68 + bcol] = rb[j];
            __syncthreads();
        }
    }

    // ---- epilogue: bias + relu, float4 stores ----
    float bv[4] = {0.f, 0.f, 0.f, 0.f};
    int gc = tx * 4;
    if (bias && gc < Nc) {
        bv[0] = bias[gc + 0]; bv[1] = bias[gc + 1];
        bv[2] = bias[gc + 2]; bv[3] = bias[gc + 3];
    }
#pragma unroll
    for (int ic = 0; ic < 2; ++ic) {
#pragma unroll
        for (int i = 0; i < 4; ++i) {
            int gr = bm + ic * 64 + ty * 4 + i;
            if (gr >= M || gc >= Nc) continue;
            float4 v;
            v.x = acc[ic * 4 + i][0] + bv[0];
            v.y = acc[ic * 4 + i][1] + bv[1];
            v.z = acc[ic * 4 + i][2] + bv[2];
            v.w = acc[ic * 4 + i][3] + bv[3];
            if (doRelu) {
                v.x = fmaxf(v.x, 0.f); v.y = fmaxf(v.y, 0.f);
                v.z = fmaxf(v.z, 0.f); v.w = fmaxf(v.w, 0.f);
            }
            *(float4*)&C[(size_t)gr * Nc + gc] = v;
        }
    }
}

__device__ __forceinline__ float lrelu(float x) { return x > 0.f ? x : 0.2f * x; }
__device__ __forceinline__ int edge_src(const int* ei, int e) { return e < EE ? ei[e] : e - EE; }
__device__ __forceinline__ int edge_dst(const int* ei, int e) { return e < EE ? ei[EE + e] : e - EE; }

// ================= CSR build =================
__global__ __launch_bounds__(256) void csr_count(const int* __restrict__ ei, int* __restrict__ cnt)
{
    int e = blockIdx.x * 256 + threadIdx.x;
    if (e >= ETOT) return;
    atomicAdd(&cnt[edge_dst(ei, e)], 1);
}

__global__ __launch_bounds__(256) void scan_partial(const int* __restrict__ cnt, int* __restrict__ partial)
{
    __shared__ int s[256];
    int b = blockIdx.x;
    int gi = b * 512 + threadIdx.x;
    int v = 0;
    if (gi < NN) v += cnt[gi];
    if (gi + 256 < NN) v += cnt[gi + 256];
    s[threadIdx.x] = v;
    __syncthreads();
    for (int off = 128; off > 0; off >>= 1) {
        if (threadIdx.x < off) s[threadIdx.x] += s[threadIdx.x + off];
        __syncthreads();
    }
    if (threadIdx.x == 0) partial[b] = s[0];
}

__global__ __launch_bounds__(256) void scan_top(int* __restrict__ partial, int nb)
{
    __shared__ int s[256];
    int tid = threadIdx.x;
    s[tid] = (tid < nb) ? partial[tid] : 0;
    __syncthreads();
    for (int off = 1; off < 256; off <<= 1) {
        int t = (tid >= off) ? s[tid - off] : 0;
        __syncthreads();
        s[tid] += t;
        __syncthreads();
    }
    if (tid < nb) partial[tid] = (tid == 0) ? 0 : s[tid - 1];
}

__global__ __launch_bounds__(256) void scan_final(
    const int* __restrict__ cnt, const int* __restrict__ partial, int* __restrict__ row_ptr)
{
    __shared__ int s[512];
    int b = blockIdx.x;
    int tid = threadIdx.x;
    int g0 = b * 512 + tid, g1 = b * 512 + tid + 256;
    s[tid]       = (g0 < NN) ? cnt[g0] : 0;
    s[tid + 256] = (g1 < NN) ? cnt[g1] : 0;
    __syncthreads();
#pragma unroll
    for (int d = 0; d < 9; ++d) {
        int stride = 1 << d, n = 256 >> d;
        if (tid < n) s[(2 * tid + 2) * stride - 1] += s[(2 * tid + 1) * stride - 1];
        __syncthreads();
    }
    if (tid == 0) s[511] = 0;
    __syncthreads();
#pragma unroll
    for (int d = 8; d >= 0; --d) {
        int stride = 1 << d, n = 256 >> d;
        if (tid < n) {
            int i1 = (2 * tid + 1) * stride - 1, i2 = (2 * tid + 2) * stride - 1;
            int t = s[i1];
            s[i1] = s[i2];
            s[i2] += t;
        }
        __syncthreads();
    }
    int off = partial[b];
    if (g0 < NN) row_ptr[g0] = s[tid] + off;
    if (g1 < NN) row_ptr[g1] = s[tid + 256] + off;
}

__global__ __launch_bounds__(256) void cursor_init(const int* __restrict__ row_ptr, int* __restrict__ cur)
{
    int i = blockIdx.x * 256 + threadIdx.x;
    if (i < NN) cur[i] = row_ptr[i];
    if (i == 0) ((int*)row_ptr)[NN] = ETOT;
}

__global__ __launch_bounds__(256) void csr_fill(
    const int* __restrict__ ei, int* __restrict__ cur, int* __restrict__ col_src)
{
    int e = blockIdx.x * 256 + threadIdx.x;
    if (e >= ETOT) return;
    int d = edge_dst(ei, e);
    int pos = atomicAdd(&cur[d], 1);
    col_src[pos] = edge_src(ei, e);
}

// ================= per-layer weight precomputes =================
__global__ __launch_bounds__(256) void att_vec_kernel(
    const float* __restrict__ W, const float* __restrict__ attS,
    const float* __restrict__ attD, float* __restrict__ vs, float* __restrict__ vd)
{
    int tid = threadIdx.x;           // tid = k*4+h
    int k = tid >> 2, h = tid & 3;
    const float* wr = W + (size_t)k * 256 + h * 64;
    const float* as = attS + h * 64;
    const float* ad = attD + h * 64;
    float ss = 0.f, sd = 0.f;
#pragma unroll
    for (int j = 0; j < 64; ++j) {
        float wv = wr[j];
        ss += wv * as[j];
        sd += wv * ad[j];
    }
    vs[tid] = ss;
    vd[tid] = sd;
}

__global__ __launch_bounds__(256) void permW_kernel(const float* __restrict__ W, float* __restrict__ B2)
{
    int i = blockIdx.x * 256 + threadIdx.x;   // i = r*64+j, r = h*64+k
    if (i >= 256 * 64) return;
    int r = i >> 6, j = i & 63;
    int h = r >> 6, k = r & 63;
    B2[i] = W[(size_t)k * 256 + h * 64 + j];
}

// ================= attention scores directly from x =================
__global__ __launch_bounds__(256) void scores_x_kernel(
    const float* __restrict__ x, const float* __restrict__ vs,
    const float* __restrict__ vd, float4* __restrict__ a4s, float4* __restrict__ a4d)
{
    __shared__ float4 svs[64], svd[64];
    int tid = threadIdx.x;
    if (tid < 64) {
        svs[tid] = ((const float4*)vs)[tid];
        svd[tid] = ((const float4*)vd)[tid];
    }
    __syncthreads();
    int n = blockIdx.x * 256 + tid;
    if (n >= NN) return;
    const float4* xp = (const float4*)(x + (size_t)n * 64);
    float4 as = {0.f, 0.f, 0.f, 0.f}, ad = {0.f, 0.f, 0.f, 0.f};
#pragma unroll
    for (int i = 0; i < 16; ++i) {
        float4 xv = xp[i];
        float4 s0 = svs[i * 4 + 0], s1 = svs[i * 4 + 1], s2 = svs[i * 4 + 2], s3 = svs[i * 4 + 3];
        float4 d0 = svd[i * 4 + 0], d1 = svd[i * 4 + 1], d2 = svd[i * 4 + 2], d3 = svd[i * 4 + 3];
        as.x += xv.x * s0.x + xv.y * s1.x + xv.z * s2.x + xv.w * s3.x;
        as.y += xv.x * s0.y + xv.y * s1.y + xv.z * s2.y + xv.w * s3.y;
        as.z += xv.x * s0.z + xv.y * s1.z + xv.z * s2.z + xv.w * s3.z;
        as.w += xv.x * s0.w + xv.y * s1.w + xv.z * s2.w + xv.w * s3.w;
        ad.x += xv.x * d0.x + xv.y * d1.x + xv.z * d2.x + xv.w * d3.x;
        ad.y += xv.x * d0.y + xv.y * d1.y + xv.z * d2.y + xv.w * d3.y;
        ad.z += xv.x * d0.z + xv.y * d1.z + xv.z * d2.z + xv.w * d3.z;
        ad.w += xv.x * d0.w + xv.y * d1.w + xv.z * d2.w + xv.w * d3.w;
    }
    a4s[n] = as;
    a4d[n] = ad;
}

// ================= softmax per CSR row (4-way unrolled gathers) =================
__global__ __launch_bounds__(256) void row_softmax(
    const int* __restrict__ row_ptr, const int* __restrict__ col_src,
    const float4* __restrict__ a4s, const float4* __restrict__ a4d,
    float4* __restrict__ w, float4* __restrict__ inv)
{
    int d = blockIdx.x * 256 + threadIdx.x;
    if (d >= NN) return;
    int rs = row_ptr[d], re = row_ptr[d + 1];
    float4 ad = a4d[d];
    float mx = -1e30f, my = -1e30f, mz = -1e30f, mw = -1e30f;

    int e = rs;
    for (; e + 4 <= re; e += 4) {
        int s0 = col_src[e + 0], s1 = col_src[e + 1];
        int s2 = col_src[e + 2], s3 = col_src[e + 3];
        float4 v0 = a4s[s0], v1 = a4s[s1], v2 = a4s[s2], v3 = a4s[s3];
        float4 al0, al1, al2, al3;
        al0.x = lrelu(v0.x + ad.x); al0.y = lrelu(v0.y + ad.y); al0.z = lrelu(v0.z + ad.z); al0.w = lrelu(v0.w + ad.w);
        al1.x = lrelu(v1.x + ad.x); al1.y = lrelu(v1.y + ad.y); al1.z = lrelu(v1.z + ad.z); al1.w = lrelu(v1.w + ad.w);
        al2.x = lrelu(v2.x + ad.x); al2.y = lrelu(v2.y + ad.y); al2.z = lrelu(v2.z + ad.z); al2.w = lrelu(v2.w + ad.w);
        al3.x = lrelu(v3.x + ad.x); al3.y = lrelu(v3.y + ad.y); al3.z = lrelu(v3.z + ad.z); al3.w = lrelu(v3.w + ad.w);
        w[e + 0] = al0; w[e + 1] = al1; w[e + 2] = al2; w[e + 3] = al3;
        mx = fmaxf(fmaxf(fmaxf(mx, al0.x), fmaxf(al1.x, al2.x)), al3.x);
        my = fmaxf(fmaxf(fmaxf(my, al0.y), fmaxf(al1.y, al2.y)), al3.y);
        mz = fmaxf(fmaxf(fmaxf(mz, al0.z), fmaxf(al1.z, al2.z)), al3.z);
        mw = fmaxf(fmaxf(fmaxf(mw, al0.w), fmaxf(al1.w, al2.w)), al3.w);
    }
    for (; e < re; ++e) {
        int s = col_src[e];
        float4 v = a4s[s];
        float4 al;
        al.x = lrelu(v.x + ad.x); al.y = lrelu(v.y + ad.y);
        al.z = lrelu(v.z + ad.z); al.w = lrelu(v.w + ad.w);
        w[e] = al;
        mx = fmaxf(mx, al.x); my = fmaxf(my, al.y);
        mz = fmaxf(mz, al.z); mw = fmaxf(mw, al.w);
    }

    float sx = 0.f, sy = 0.f, sz = 0.f, sw = 0.f;
    e = rs;
    for (; e + 2 <= re; e += 2) {
        float4 a0 = w[e], a1 = w[e + 1];
        a0.x = expf(a0.x - mx); a0.y = expf(a0.y - my); a0.z = expf(a0.z - mz); a0.w = expf(a0.w - mw);
        a1.x = expf(a1.x - mx); a1.y = expf(a1.y - my); a1.z = expf(a1.z - mz); a1.w = expf(a1.w - mw);
        w[e] = a0; w[e + 1] = a1;
        sx += a0.x + a1.x; sy += a0.y + a1.y; sz += a0.z + a1.z; sw += a0.w + a1.w;
    }
    for (; e < re; ++e) {
        float4 a0 = w[e];
        a0.x = expf(a0.x - mx); a0.y = expf(a0.y - my);
        a0.z = expf(a0.z - mz); a0.w = expf(a0.w - mw);
        w[e] = a0;
        sx += a0.x; sy += a0.y; sz += a0.z; sw += a0.w;
    }
    float4 iv;
    iv.x = 0.25f / sx; iv.y = 0.25f / sy; iv.z = 0.25f / sz; iv.w = 0.25f / sw;
    inv[d] = iv;
}

// ================= gather aggregation in x-space (wave per dst, 4-way unrolled) =================
__global__ __launch_bounds__(256) void gather_agg_x(
    const int* __restrict__ row_ptr, const int* __restrict__ col_src,
    const float4* __restrict__ w, const float4* __restrict__ inv,
    const float* __restrict__ x, float* __restrict__ agg)
{
    int d = (blockIdx.x * 256 + threadIdx.x) >> 6;
    int lane = threadIdx.x & 63;
    if (d >= NN) return;
    int rs = row_ptr[d], re = row_ptr[d + 1];
    float a0 = 0.f, a1 = 0.f, a2 = 0.f, a3 = 0.f;

    int e = rs;
    for (; e + 4 <= re; e += 4) {
        int s0 = col_src[e + 0], s1 = col_src[e + 1];
        int s2 = col_src[e + 2], s3 = col_src[e + 3];
        float4 w0 = w[e + 0], w1 = w[e + 1], w2 = w[e + 2], w3 = w[e + 3];
        float x0 = x[(size_t)s0 * 64 + lane];
        float x1 = x[(size_t)s1 * 64 + lane];
        float x2 = x[(size_t)s2 * 64 + lane];
        float x3 = x[(size_t)s3 * 64 + lane];
        a0 += w0.x * x0 + w1.x * x1 + w2.x * x2 + w3.x * x3;
        a1 += w0.y * x0 + w1.y * x1 + w2.y * x2 + w3.y * x3;
        a2 += w0.z * x0 + w1.z * x1 + w2.z * x2 + w3.z * x3;
        a3 += w0.w * x0 + w1.w * x1 + w2.w * x2 + w3.w * x3;
    }
    for (; e < re; ++e) {
        float4 pv = w[e];
        int s = col_src[e];
        float xv = x[(size_t)s * 64 + lane];
        a0 += pv.x * xv; a1 += pv.y * xv; a2 += pv.z * xv; a3 += pv.w * xv;
    }
    float4 iv = inv[d];
    float* op = agg + (size_t)d * 256;
    op[lane]       = a0 * iv.x;
    op[64 + lane]  = a1 * iv.y;
    op[128 + lane] = a2 * iv.z;
    op[192 + lane] = a3 * iv.w;
}

// ---------------- host-side GAT layer ----------------
static void gat_layer(float* x /* in/out [N,64] */, const float* W, const float* attS,
                      const float* attD, const float* b, const int* row_ptr, const int* col_src,
                      float* agg, float4* a4s, float4* a4d, float4* inv, float4* w,
                      float* vs, float* vd, float* B2, hipStream_t stream)
{
    att_vec_kernel<<<1, 256, 0, stream>>>(W, attS, attD, vs, vd);
    permW_kernel<<<64, 256, 0, stream>>>(W, B2);
    scores_x_kernel<<<(NN + 255) / 256, 256, 0, stream>>>(x, vs, vd, a4s, a4d);
    row_softmax<<<(NN + 255) / 256, 256, 0, stream>>>(row_ptr, col_src, a4s, a4d, w, inv);
    gather_agg_x<<<(NN * 64 + 255) / 256, 256, 0, stream>>>(row_ptr, col_src, w, inv, x, agg);
    // x_out = relu(agg @ B2 + b)   (0.25 folded into inv)
    gemm_kernel<<<(NN + 127) / 128, 256, 0, stream>>>(agg, B2, b, x, NN, 256, 64, 1);
}

extern "C" void kernel_launch(void* const* d_in, const int* in_sizes, int n_in,
                              void* d_out, int out_size, void* d_ws, size_t ws_size,
                              hipStream_t stream)
{
    const float* obs     = (const float*)d_in[0];
    const int*   ei      = (const int*)d_in[1];
    const float* enc_w1  = (const float*)d_in[2];
    const float* enc_b1  = (const float*)d_in[3];
    const float* enc_w2  = (const float*)d_in[4];
    const float* enc_b2  = (const float*)d_in[5];
    const float* gat1_w  = (const float*)d_in[6];
    const float* gat1_as = (const float*)d_in[7];
    const float* gat1_ad = (const float*)d_in[8];
    const float* gat1_b  = (const float*)d_in[9];
    const float* gat2_w  = (const float*)d_in[10];
    const float* gat2_as = (const float*)d_in[11];
    const float* gat2_ad = (const float*)d_in[12];
    const float* gat2_b  = (const float*)d_in[13];
    const float* dec_w1  = (const float*)d_in[14];
    const float* dec_b1  = (const float*)d_in[15];
    const float* dec_w2  = (const float*)d_in[16];
    const float* dec_b2  = (const float*)d_in[17];

    float* ws = (float*)d_ws;
    float* bufA    = ws;                                   // [N,64]
    float* bufB    = bufA + (size_t)NN * 64;               // [N,64]  (x)
    float* agg     = bufB + (size_t)NN * 64;               // [N,256]
    float4* a4s    = (float4*)(agg + (size_t)NN * 256);    // [N]
    float4* a4d    = a4s + NN;                             // [N]
    float4* inv    = a4d + NN;                             // [N]
    float4* w      = inv + NN;                             // [ETOT]
    int* row_ptr   = (int*)(w + (size_t)ETOT);             // [N+1] (+pad)
    int* cnt       = row_ptr + NN + 4;                     // [N]
    int* cur       = cnt + NN;                             // [N]
    int* col_src   = cur + NN;                             // [ETOT]
    int* partial   = col_src + ETOT;                       // [256]
    float* vs      = (float*)(partial + 256);              // [256]
    float* vd      = vs + 256;                             // [256]
    float* B2      = vd + 256;                             // [256*64]

    const int NB = (NN + 511) / 512;
    const int GB = (NN + 127) / 128;

    // ---- CSR build (once, reused by both GAT layers) ----
    hipMemsetAsync(cnt, 0, (size_t)NN * sizeof(int), stream);
    csr_count<<<(ETOT + 255) / 256, 256, 0, stream>>>(ei, cnt);
    scan_partial<<<NB, 256, 0, stream>>>(cnt, partial);
    scan_top<<<1, 256, 0, stream>>>(partial, NB);
    scan_final<<<NB, 256, 0, stream>>>(cnt, partial, row_ptr);
    cursor_init<<<(NN + 255) / 256, 256, 0, stream>>>(row_ptr, cur);
    csr_fill<<<(ETOT + 255) / 256, 256, 0, stream>>>(ei, cur, col_src);

    // ---- encoder ----
    gemm_kernel<<<GB, 256, 0, stream>>>(obs, enc_w1, enc_b1, bufA, NN, 128, 64, 1);
    gemm_kernel<<<GB, 256, 0, stream>>>(bufA, enc_w2, enc_b2, bufB, NN, 64, 64, 0);

    // ---- GAT layers (x lives in bufB) ----
    gat_layer(bufB, gat1_w, gat1_as, gat1_ad, gat1_b, row_ptr, col_src, agg, a4s, a4d, inv, w, vs, vd, B2, stream);
    gat_layer(bufB, gat2_w, gat2_as, gat2_ad, gat2_b, row_ptr, col_src, agg, a4s, a4d, inv, w, vs, vd, B2, stream);

    // ---- decoder ----
    gemm_kernel<<<GB, 256, 0, stream>>>(bufB, dec_w1, dec_b1, bufA, NN, 64, 64, 1);
    gemm_kernel<<<GB, 256, 0, stream>>>(bufA, dec_w2, dec_b2, (float*)d_out, NN, 64, 32, 0);
}

// Round 9
// 543.100 us; speedup vs baseline: 1.2473x; 1.2473x over previous
//
#include <hip/hip_runtime.h>
#include <math.h>

#define NN 100000
#define EE 800000
#define ETOT (EE + NN)
// HID=64, HEADS=4, OBS=128, ACT=32

// ---------------- GEMM: C[M,Nc] = A[M,K] @ B[K,Nc] (+bias, optional relu) ----------------
// BM=128, BN=64 (gy=1, A fetched once), BK=16, 128 threads, 8x8 micro-tile.
// Single-buffered LDS (R7 dbuf regressed: VGPR 236, occ 8%). K % 16 == 0; Nc <= 64, Nc % 4 == 0.
// sA stride 132: transpose-write 2-way (free); read = 8-lane broadcast of 8 distinct
// bank-quads (conflict-free). sB stride 68: read quads broadcast x8, conflict-free.
__global__ __launch_bounds__(128) void gemm_kernel(
    const float* __restrict__ A, const float* __restrict__ B,
    const float* __restrict__ bias, float* __restrict__ C,
    int M, int K, int Nc, int doRelu)
{
    __shared__ __align__(16) float sA[16 * 132];  // [k][row 0..127]
    __shared__ __align__(16) float sB[16 * 68];   // [k][col 0..63]

    const int bm = blockIdx.x * 128;
    const int tid = threadIdx.x;
    const int ty = tid >> 3;   // 0..15 -> rows ty*4+i and 64+ty*4+i
    const int tx = tid & 7;    // 0..7  -> cols tx*4+j and 32+tx*4+j

    float acc[8][8] = {};

    for (int k0 = 0; k0 < K; k0 += 16) {
        // ---- stage A: 128 rows x 16 k, transpose to [k][row] ----
#pragma unroll
        for (int p = 0; p < 4; ++p) {
            int q = tid + p * 128;
            int r = q >> 2;          // 0..127
            int c4 = q & 3;          // which float4 of the 16-k strip
            int gr = bm + r;
            float4 v = {0.f, 0.f, 0.f, 0.f};
            if (gr < M) v = *(const float4*)&A[(size_t)gr * K + k0 + c4 * 4];
            sA[(c4 * 4 + 0) * 132 + r] = v.x;
            sA[(c4 * 4 + 1) * 132 + r] = v.y;
            sA[(c4 * 4 + 2) * 132 + r] = v.z;
            sA[(c4 * 4 + 3) * 132 + r] = v.w;
        }
        // ---- stage B: 16 k x 64 cols ----
#pragma unroll
        for (int p = 0; p < 2; ++p) {
            int q = tid + p * 128;
            int row = q >> 4;        // 0..15
            int c4 = (q & 15) * 4;   // 0..60
            float4 v = {0.f, 0.f, 0.f, 0.f};
            if (c4 < Nc) v = *(const float4*)&B[(size_t)(k0 + row) * Nc + c4];
            *(float4*)&sB[row * 68 + c4] = v;
        }
        __syncthreads();
#pragma unroll
        for (int k = 0; k < 16; ++k) {
            float4 a0 = *(const float4*)&sA[k * 132 + ty * 4];
            float4 a1 = *(const float4*)&sA[k * 132 + 64 + ty * 4];
            float4 b0 = *(const float4*)&sB[k * 68 + tx * 4];
            float4 b1 = *(const float4*)&sB[k * 68 + 32 + tx * 4];
            float a[8] = {a0.x, a0.y, a0.z, a0.w, a1.x, a1.y, a1.z, a1.w};
            float b[8] = {b0.x, b0.y, b0.z, b0.w, b1.x, b1.y, b1.z, b1.w};
#pragma unroll
            for (int i = 0; i < 8; ++i)
#pragma unroll
                for (int j = 0; j < 8; ++j)
                    acc[i][j] = fmaf(a[i], b[j], acc[i][j]);
        }
        __syncthreads();
    }

    // ---- epilogue: bias + relu, float4 stores ----
    const int gc0 = tx * 4, gc1 = 32 + tx * 4;
    float bv[8] = {0.f, 0.f, 0.f, 0.f, 0.f, 0.f, 0.f, 0.f};
    if (bias) {
        if (gc0 < Nc) { bv[0] = bias[gc0]; bv[1] = bias[gc0 + 1]; bv[2] = bias[gc0 + 2]; bv[3] = bias[gc0 + 3]; }
        if (gc1 < Nc) { bv[4] = bias[gc1]; bv[5] = bias[gc1 + 1]; bv[6] = bias[gc1 + 2]; bv[7] = bias[gc1 + 3]; }
    }
#pragma unroll
    for (int rg = 0; rg < 2; ++rg) {
#pragma unroll
        for (int i = 0; i < 4; ++i) {
            int gr = bm + rg * 64 + ty * 4 + i;
            if (gr >= M) continue;
            if (gc0 < Nc) {
                float4 v;
                v.x = acc[rg * 4 + i][0] + bv[0];
                v.y = acc[rg * 4 + i][1] + bv[1];
                v.z = acc[rg * 4 + i][2] + bv[2];
                v.w = acc[rg * 4 + i][3] + bv[3];
                if (doRelu) { v.x = fmaxf(v.x, 0.f); v.y = fmaxf(v.y, 0.f); v.z = fmaxf(v.z, 0.f); v.w = fmaxf(v.w, 0.f); }
                *(float4*)&C[(size_t)gr * Nc + gc0] = v;
            }
            if (gc1 < Nc) {
                float4 v;
                v.x = acc[rg * 4 + i][4] + bv[4];
                v.y = acc[rg * 4 + i][5] + bv[5];
                v.z = acc[rg * 4 + i][6] + bv[6];
                v.w = acc[rg * 4 + i][7] + bv[7];
                if (doRelu) { v.x = fmaxf(v.x, 0.f); v.y = fmaxf(v.y, 0.f); v.z = fmaxf(v.z, 0.f); v.w = fmaxf(v.w, 0.f); }
                *(float4*)&C[(size_t)gr * Nc + gc1] = v;
            }
        }
    }
}

__device__ __forceinline__ float lrelu(float x) { return x > 0.f ? x : 0.2f * x; }
__device__ __forceinline__ int edge_src(const int* ei, int e) { return e < EE ? ei[e] : e - EE; }
__device__ __forceinline__ int edge_dst(const int* ei, int e) { return e < EE ? ei[EE + e] : e - EE; }

// ================= CSR build =================
__global__ __launch_bounds__(256) void csr_count(const int* __restrict__ ei, int* __restrict__ cnt)
{
    int e = blockIdx.x * 256 + threadIdx.x;
    if (e >= ETOT) return;
    atomicAdd(&cnt[edge_dst(ei, e)], 1);
}

__global__ __launch_bounds__(256) void scan_partial(const int* __restrict__ cnt, int* __restrict__ partial)
{
    __shared__ int s[256];
    int b = blockIdx.x;
    int gi = b * 512 + threadIdx.x;
    int v = 0;
    if (gi < NN) v += cnt[gi];
    if (gi + 256 < NN) v += cnt[gi + 256];
    s[threadIdx.x] = v;
    __syncthreads();
    for (int off = 128; off > 0; off >>= 1) {
        if (threadIdx.x < off) s[threadIdx.x] += s[threadIdx.x + off];
        __syncthreads();
    }
    if (threadIdx.x == 0) partial[b] = s[0];
}

__global__ __launch_bounds__(256) void scan_top(int* __restrict__ partial, int nb)
{
    __shared__ int s[256];
    int tid = threadIdx.x;
    s[tid] = (tid < nb) ? partial[tid] : 0;
    __syncthreads();
    for (int off = 1; off < 256; off <<= 1) {
        int t = (tid >= off) ? s[tid - off] : 0;
        __syncthreads();
        s[tid] += t;
        __syncthreads();
    }
    if (tid < nb) partial[tid] = (tid == 0) ? 0 : s[tid - 1];
}

__global__ __launch_bounds__(256) void scan_final(
    const int* __restrict__ cnt, const int* __restrict__ partial, int* __restrict__ row_ptr)
{
    __shared__ int s[512];
    int b = blockIdx.x;
    int tid = threadIdx.x;
    int g0 = b * 512 + tid, g1 = b * 512 + tid + 256;
    s[tid]       = (g0 < NN) ? cnt[g0] : 0;
    s[tid + 256] = (g1 < NN) ? cnt[g1] : 0;
    __syncthreads();
#pragma unroll
    for (int d = 0; d < 9; ++d) {
        int stride = 1 << d, n = 256 >> d;
        if (tid < n) s[(2 * tid + 2) * stride - 1] += s[(2 * tid + 1) * stride - 1];
        __syncthreads();
    }
    if (tid == 0) s[511] = 0;
    __syncthreads();
#pragma unroll
    for (int d = 8; d >= 0; --d) {
        int stride = 1 << d, n = 256 >> d;
        if (tid < n) {
            int i1 = (2 * tid + 1) * stride - 1, i2 = (2 * tid + 2) * stride - 1;
            int t = s[i1];
            s[i1] = s[i2];
            s[i2] += t;
        }
        __syncthreads();
    }
    int off = partial[b];
    if (g0 < NN) row_ptr[g0] = s[tid] + off;
    if (g1 < NN) row_ptr[g1] = s[tid + 256] + off;
}

__global__ __launch_bounds__(256) void cursor_init(const int* __restrict__ row_ptr, int* __restrict__ cur)
{
    int i = blockIdx.x * 256 + threadIdx.x;
    if (i < NN) cur[i] = row_ptr[i];
    if (i == 0) ((int*)row_ptr)[NN] = ETOT;
}

__global__ __launch_bounds__(256) void csr_fill(
    const int* __restrict__ ei, int* __restrict__ cur, int* __restrict__ col_src)
{
    int e = blockIdx.x * 256 + threadIdx.x;
    if (e >= ETOT) return;
    int d = edge_dst(ei, e);
    int pos = atomicAdd(&cur[d], 1);
    col_src[pos] = edge_src(ei, e);
}

// ================= per-layer weight precomputes =================
__global__ __launch_bounds__(256) void att_vec_kernel(
    const float* __restrict__ W, const float* __restrict__ attS,
    const float* __restrict__ attD, float* __restrict__ vs, float* __restrict__ vd)
{
    int tid = threadIdx.x;           // tid = k*4+h
    int k = tid >> 2, h = tid & 3;
    const float* wr = W + (size_t)k * 256 + h * 64;
    const float* as = attS + h * 64;
    const float* ad = attD + h * 64;
    float ss = 0.f, sd = 0.f;
#pragma unroll
    for (int j = 0; j < 64; ++j) {
        float wv = wr[j];
        ss += wv * as[j];
        sd += wv * ad[j];
    }
    vs[tid] = ss;
    vd[tid] = sd;
}

__global__ __launch_bounds__(256) void permW_kernel(const float* __restrict__ W, float* __restrict__ B2)
{
    int i = blockIdx.x * 256 + threadIdx.x;   // i = r*64+j, r = h*64+k
    if (i >= 256 * 64) return;
    int r = i >> 6, j = i & 63;
    int h = r >> 6, k = r & 63;
    B2[i] = W[(size_t)k * 256 + h * 64 + j];
}

// ================= attention scores directly from x =================
__global__ __launch_bounds__(256) void scores_x_kernel(
    const float* __restrict__ x, const float* __restrict__ vs,
    const float* __restrict__ vd, float4* __restrict__ a4s, float4* __restrict__ a4d)
{
    __shared__ float4 svs[64], svd[64];
    int tid = threadIdx.x;
    if (tid < 64) {
        svs[tid] = ((const float4*)vs)[tid];
        svd[tid] = ((const float4*)vd)[tid];
    }
    __syncthreads();
    int n = blockIdx.x * 256 + tid;
    if (n >= NN) return;
    const float4* xp = (const float4*)(x + (size_t)n * 64);
    float4 as = {0.f, 0.f, 0.f, 0.f}, ad = {0.f, 0.f, 0.f, 0.f};
#pragma unroll
    for (int i = 0; i < 16; ++i) {
        float4 xv = xp[i];
        float4 s0 = svs[i * 4 + 0], s1 = svs[i * 4 + 1], s2 = svs[i * 4 + 2], s3 = svs[i * 4 + 3];
        float4 d0 = svd[i * 4 + 0], d1 = svd[i * 4 + 1], d2 = svd[i * 4 + 2], d3 = svd[i * 4 + 3];
        as.x += xv.x * s0.x + xv.y * s1.x + xv.z * s2.x + xv.w * s3.x;
        as.y += xv.x * s0.y + xv.y * s1.y + xv.z * s2.y + xv.w * s3.y;
        as.z += xv.x * s0.z + xv.y * s1.z + xv.z * s2.z + xv.w * s3.z;
        as.w += xv.x * s0.w + xv.y * s1.w + xv.z * s2.w + xv.w * s3.w;
        ad.x += xv.x * d0.x + xv.y * d1.x + xv.z * d2.x + xv.w * d3.x;
        ad.y += xv.x * d0.y + xv.y * d1.y + xv.z * d2.y + xv.w * d3.y;
        ad.z += xv.x * d0.z + xv.y * d1.z + xv.z * d2.z + xv.w * d3.z;
        ad.w += xv.x * d0.w + xv.y * d1.w + xv.z * d2.w + xv.w * d3.w;
    }
    a4s[n] = as;
    a4d[n] = ad;
}

// ================= softmax per CSR row (4-way unrolled gathers) =================
__global__ __launch_bounds__(256) void row_softmax(
    const int* __restrict__ row_ptr, const int* __restrict__ col_src,
    const float4* __restrict__ a4s, const float4* __restrict__ a4d,
    float4* __restrict__ w, float4* __restrict__ inv)
{
    int d = blockIdx.x * 256 + threadIdx.x;
    if (d >= NN) return;
    int rs = row_ptr[d], re = row_ptr[d + 1];
    float4 ad = a4d[d];
    float mx = -1e30f, my = -1e30f, mz = -1e30f, mw = -1e30f;

    int e = rs;
    for (; e + 4 <= re; e += 4) {
        int s0 = col_src[e + 0], s1 = col_src[e + 1];
        int s2 = col_src[e + 2], s3 = col_src[e + 3];
        float4 v0 = a4s[s0], v1 = a4s[s1], v2 = a4s[s2], v3 = a4s[s3];
        float4 al0, al1, al2, al3;
        al0.x = lrelu(v0.x + ad.x); al0.y = lrelu(v0.y + ad.y); al0.z = lrelu(v0.z + ad.z); al0.w = lrelu(v0.w + ad.w);
        al1.x = lrelu(v1.x + ad.x); al1.y = lrelu(v1.y + ad.y); al1.z = lrelu(v1.z + ad.z); al1.w = lrelu(v1.w + ad.w);
        al2.x = lrelu(v2.x + ad.x); al2.y = lrelu(v2.y + ad.y); al2.z = lrelu(v2.z + ad.z); al2.w = lrelu(v2.w + ad.w);
        al3.x = lrelu(v3.x + ad.x); al3.y = lrelu(v3.y + ad.y); al3.z = lrelu(v3.z + ad.z); al3.w = lrelu(v3.w + ad.w);
        w[e + 0] = al0; w[e + 1] = al1; w[e + 2] = al2; w[e + 3] = al3;
        mx = fmaxf(fmaxf(fmaxf(mx, al0.x), fmaxf(al1.x, al2.x)), al3.x);
        my = fmaxf(fmaxf(fmaxf(my, al0.y), fmaxf(al1.y, al2.y)), al3.y);
        mz = fmaxf(fmaxf(fmaxf(mz, al0.z), fmaxf(al1.z, al2.z)), al3.z);
        mw = fmaxf(fmaxf(fmaxf(mw, al0.w), fmaxf(al1.w, al2.w)), al3.w);
    }
    for (; e < re; ++e) {
        int s = col_src[e];
        float4 v = a4s[s];
        float4 al;
        al.x = lrelu(v.x + ad.x); al.y = lrelu(v.y + ad.y);
        al.z = lrelu(v.z + ad.z); al.w = lrelu(v.w + ad.w);
        w[e] = al;
        mx = fmaxf(mx, al.x); my = fmaxf(my, al.y);
        mz = fmaxf(mz, al.z); mw = fmaxf(mw, al.w);
    }

    float sx = 0.f, sy = 0.f, sz = 0.f, sw = 0.f;
    e = rs;
    for (; e + 2 <= re; e += 2) {
        float4 a0 = w[e], a1 = w[e + 1];
        a0.x = expf(a0.x - mx); a0.y = expf(a0.y - my); a0.z = expf(a0.z - mz); a0.w = expf(a0.w - mw);
        a1.x = expf(a1.x - mx); a1.y = expf(a1.y - my); a1.z = expf(a1.z - mz); a1.w = expf(a1.w - mw);
        w[e] = a0; w[e + 1] = a1;
        sx += a0.x + a1.x; sy += a0.y + a1.y; sz += a0.z + a1.z; sw += a0.w + a1.w;
    }
    for (; e < re; ++e) {
        float4 a0 = w[e];
        a0.x = expf(a0.x - mx); a0.y = expf(a0.y - my);
        a0.z = expf(a0.z - mz); a0.w = expf(a0.w - mw);
        w[e] = a0;
        sx += a0.x; sy += a0.y; sz += a0.z; sw += a0.w;
    }
    float4 iv;
    iv.x = 0.25f / sx; iv.y = 0.25f / sy; iv.z = 0.25f / sz; iv.w = 0.25f / sw;
    inv[d] = iv;
}

// ================= gather aggregation in x-space (wave per dst, 4-way unrolled) =================
__global__ __launch_bounds__(256) void gather_agg_x(
    const int* __restrict__ row_ptr, const int* __restrict__ col_src,
    const float4* __restrict__ w, const float4* __restrict__ inv,
    const float* __restrict__ x, float* __restrict__ agg)
{
    int d = (blockIdx.x * 256 + threadIdx.x) >> 6;
    int lane = threadIdx.x & 63;
    if (d >= NN) return;
    int rs = row_ptr[d], re = row_ptr[d + 1];
    float a0 = 0.f, a1 = 0.f, a2 = 0.f, a3 = 0.f;

    int e = rs;
    for (; e + 4 <= re; e += 4) {
        int s0 = col_src[e + 0], s1 = col_src[e + 1];
        int s2 = col_src[e + 2], s3 = col_src[e + 3];
        float4 w0 = w[e + 0], w1 = w[e + 1], w2 = w[e + 2], w3 = w[e + 3];
        float x0 = x[(size_t)s0 * 64 + lane];
        float x1 = x[(size_t)s1 * 64 + lane];
        float x2 = x[(size_t)s2 * 64 + lane];
        float x3 = x[(size_t)s3 * 64 + lane];
        a0 += w0.x * x0 + w1.x * x1 + w2.x * x2 + w3.x * x3;
        a1 += w0.y * x0 + w1.y * x1 + w2.y * x2 + w3.y * x3;
        a2 += w0.z * x0 + w1.z * x1 + w2.z * x2 + w3.z * x3;
        a3 += w0.w * x0 + w1.w * x1 + w2.w * x2 + w3.w * x3;
    }
    for (; e < re; ++e) {
        float4 pv = w[e];
        int s = col_src[e];
        float xv = x[(size_t)s * 64 + lane];
        a0 += pv.x * xv; a1 += pv.y * xv; a2 += pv.z * xv; a3 += pv.w * xv;
    }
    float4 iv = inv[d];
    float* op = agg + (size_t)d * 256;
    op[lane]       = a0 * iv.x;
    op[64 + lane]  = a1 * iv.y;
    op[128 + lane] = a2 * iv.z;
    op[192 + lane] = a3 * iv.w;
}

// ---------------- host-side GAT layer ----------------
static void gat_layer(float* x /* in/out [N,64] */, const float* W, const float* attS,
                      const float* attD, const float* b, const int* row_ptr, const int* col_src,
                      float* agg, float4* a4s, float4* a4d, float4* inv, float4* w,
                      float* vs, float* vd, float* B2, hipStream_t stream)
{
    att_vec_kernel<<<1, 256, 0, stream>>>(W, attS, attD, vs, vd);
    permW_kernel<<<64, 256, 0, stream>>>(W, B2);
    scores_x_kernel<<<(NN + 255) / 256, 256, 0, stream>>>(x, vs, vd, a4s, a4d);
    row_softmax<<<(NN + 255) / 256, 256, 0, stream>>>(row_ptr, col_src, a4s, a4d, w, inv);
    gather_agg_x<<<(NN * 64 + 255) / 256, 256, 0, stream>>>(row_ptr, col_src, w, inv, x, agg);
    // x_out = relu(agg @ B2 + b)   (0.25 folded into inv)
    gemm_kernel<<<(NN + 127) / 128, 128, 0, stream>>>(agg, B2, b, x, NN, 256, 64, 1);
}

extern "C" void kernel_launch(void* const* d_in, const int* in_sizes, int n_in,
                              void* d_out, int out_size, void* d_ws, size_t ws_size,
                              hipStream_t stream)
{
    const float* obs     = (const float*)d_in[0];
    const int*   ei      = (const int*)d_in[1];
    const float* enc_w1  = (const float*)d_in[2];
    const float* enc_b1  = (const float*)d_in[3];
    const float* enc_w2  = (const float*)d_in[4];
    const float* enc_b2  = (const float*)d_in[5];
    const float* gat1_w  = (const float*)d_in[6];
    const float* gat1_as = (const float*)d_in[7];
    const float* gat1_ad = (const float*)d_in[8];
    const float* gat1_b  = (const float*)d_in[9];
    const float* gat2_w  = (const float*)d_in[10];
    const float* gat2_as = (const float*)d_in[11];
    const float* gat2_ad = (const float*)d_in[12];
    const float* gat2_b  = (const float*)d_in[13];
    const float* dec_w1  = (const float*)d_in[14];
    const float* dec_b1  = (const float*)d_in[15];
    const float* dec_w2  = (const float*)d_in[16];
    const float* dec_b2  = (const float*)d_in[17];

    float* ws = (float*)d_ws;
    float* bufA    = ws;                                   // [N,64]
    float* bufB    = bufA + (size_t)NN * 64;               // [N,64]  (x)
    float* agg     = bufB + (size_t)NN * 64;               // [N,256]
    float4* a4s    = (float4*)(agg + (size_t)NN * 256);    // [N]
    float4* a4d    = a4s + NN;                             // [N]
    float4* inv    = a4d + NN;                             // [N]
    float4* w      = inv + NN;                             // [ETOT]
    int* row_ptr   = (int*)(w + (size_t)ETOT);             // [N+1] (+pad)
    int* cnt       = row_ptr + NN + 4;                     // [N]
    int* cur       = cnt + NN;                             // [N]
    int* col_src   = cur + NN;                             // [ETOT]
    int* partial   = col_src + ETOT;                       // [256]
    float* vs      = (float*)(partial + 256);              // [256]
    float* vd      = vs + 256;                             // [256]
    float* B2      = vd + 256;                             // [256*64]

    const int NB = (NN + 511) / 512;
    const int GB = (NN + 127) / 128;

    // ---- CSR build (once, reused by both GAT layers) ----
    hipMemsetAsync(cnt, 0, (size_t)NN * sizeof(int), stream);
    csr_count<<<(ETOT + 255) / 256, 256, 0, stream>>>(ei, cnt);
    scan_partial<<<NB, 256, 0, stream>>>(cnt, partial);
    scan_top<<<1, 256, 0, stream>>>(partial, NB);
    scan_final<<<NB, 256, 0, stream>>>(cnt, partial, row_ptr);
    cursor_init<<<(NN + 255) / 256, 256, 0, stream>>>(row_ptr, cur);
    csr_fill<<<(ETOT + 255) / 256, 256, 0, stream>>>(ei, cur, col_src);

    // ---- encoder ----
    gemm_kernel<<<GB, 128, 0, stream>>>(obs, enc_w1, enc_b1, bufA, NN, 128, 64, 1);
    gemm_kernel<<<GB, 128, 0, stream>>>(bufA, enc_w2, enc_b2, bufB, NN, 64, 64, 0);

    // ---- GAT layers (x lives in bufB) ----
    gat_layer(bufB, gat1_w, gat1_as, gat1_ad, gat1_b, row_ptr, col_src, agg, a4s, a4d, inv, w, vs, vd, B2, stream);
    gat_layer(bufB, gat2_w, gat2_as, gat2_ad, gat2_b, row_ptr, col_src, agg, a4s, a4d, inv, w, vs, vd, B2, stream);

    // ---- decoder ----
    gemm_kernel<<<GB, 128, 0, stream>>>(bufB, dec_w1, dec_b1, bufA, NN, 64, 64, 1);
    gemm_kernel<<<GB, 128, 0, stream>>>(bufA, dec_w2, dec_b2, (float*)d_out, NN, 64, 32, 0);
}

// Round 10
// 504.429 us; speedup vs baseline: 1.3430x; 1.0767x over previous
//
#include <hip/hip_runtime.h>
#include <math.h>

#define NN 100000
#define EE 800000
#define ETOT (EE + NN)
// HID=64, HEADS=4, OBS=128, ACT=32

// ---------------- GEMM: C[M,Nc] = A[M,K] @ B[K,Nc] (+bias, optional relu) ----------------
// BM=64, BN=64, BK=16, 256 threads, 4x4 micro-tile. Grid = M/64 = 1563 blocks -> ~6 waves/SIMD
// (R8's 128-thread BM=128 gave only 1.5 waves/SIMD -> 14% occupancy; TLP, not ILP, was the gap).
// sA/sB stride 68: a-read = 16-lane broadcast (free), b-read = 64-bank span (2-way, free),
// transpose-writes 2-way (free). K % 16 == 0; Nc <= 64, Nc % 4 == 0.
__global__ __launch_bounds__(256) void gemm_kernel(
    const float* __restrict__ A, const float* __restrict__ B,
    const float* __restrict__ bias, float* __restrict__ C,
    int M, int K, int Nc, int doRelu)
{
    __shared__ __align__(16) float sA[16 * 68];  // [k][row 0..63]
    __shared__ __align__(16) float sB[16 * 68];  // [k][col 0..63]

    const int bm = blockIdx.x * 64;
    const int tid = threadIdx.x;
    const int ty = tid >> 4;   // 0..15 -> rows ty*4+i
    const int tx = tid & 15;   // 0..15 -> cols tx*4+j

    float acc[4][4] = {};

    for (int k0 = 0; k0 < K; k0 += 16) {
        // ---- stage A: 64 rows x 16 k, transpose to [k][row] (one float4 per thread) ----
        {
            int r  = tid >> 2;        // 0..63
            int c4 = tid & 3;         // which float4 of the 16-k strip
            int gr = bm + r;
            float4 v = {0.f, 0.f, 0.f, 0.f};
            if (gr < M) v = *(const float4*)&A[(size_t)gr * K + k0 + c4 * 4];
            sA[(c4 * 4 + 0) * 68 + r] = v.x;
            sA[(c4 * 4 + 1) * 68 + r] = v.y;
            sA[(c4 * 4 + 2) * 68 + r] = v.z;
            sA[(c4 * 4 + 3) * 68 + r] = v.w;
        }
        // ---- stage B: 16 k x 64 cols (one float4 per thread) ----
        {
            int row = tid >> 4;       // 0..15
            int c4  = (tid & 15) * 4; // 0..60
            float4 v = {0.f, 0.f, 0.f, 0.f};
            if (c4 < Nc) v = *(const float4*)&B[(size_t)(k0 + row) * Nc + c4];
            *(float4*)&sB[row * 68 + c4] = v;
        }
        __syncthreads();
#pragma unroll
        for (int k = 0; k < 16; ++k) {
            float4 a0 = *(const float4*)&sA[k * 68 + ty * 4];
            float4 b0 = *(const float4*)&sB[k * 68 + tx * 4];
            float a[4] = {a0.x, a0.y, a0.z, a0.w};
            float b[4] = {b0.x, b0.y, b0.z, b0.w};
#pragma unroll
            for (int i = 0; i < 4; ++i)
#pragma unroll
                for (int j = 0; j < 4; ++j)
                    acc[i][j] = fmaf(a[i], b[j], acc[i][j]);
        }
        __syncthreads();
    }

    // ---- epilogue: bias + relu, float4 stores ----
    const int gc = tx * 4;
    float bv[4] = {0.f, 0.f, 0.f, 0.f};
    if (bias && gc < Nc) {
        bv[0] = bias[gc + 0]; bv[1] = bias[gc + 1];
        bv[2] = bias[gc + 2]; bv[3] = bias[gc + 3];
    }
    if (gc < Nc) {
#pragma unroll
        for (int i = 0; i < 4; ++i) {
            int gr = bm + ty * 4 + i;
            if (gr >= M) continue;
            float4 v;
            v.x = acc[i][0] + bv[0];
            v.y = acc[i][1] + bv[1];
            v.z = acc[i][2] + bv[2];
            v.w = acc[i][3] + bv[3];
            if (doRelu) {
                v.x = fmaxf(v.x, 0.f); v.y = fmaxf(v.y, 0.f);
                v.z = fmaxf(v.z, 0.f); v.w = fmaxf(v.w, 0.f);
            }
            *(float4*)&C[(size_t)gr * Nc + gc] = v;
        }
    }
}

__device__ __forceinline__ float lrelu(float x) { return x > 0.f ? x : 0.2f * x; }
__device__ __forceinline__ int edge_src(const int* ei, int e) { return e < EE ? ei[e] : e - EE; }
__device__ __forceinline__ int edge_dst(const int* ei, int e) { return e < EE ? ei[EE + e] : e - EE; }

// ================= CSR build =================
__global__ __launch_bounds__(256) void csr_count(const int* __restrict__ ei, int* __restrict__ cnt)
{
    int e = blockIdx.x * 256 + threadIdx.x;
    if (e >= ETOT) return;
    atomicAdd(&cnt[edge_dst(ei, e)], 1);
}

__global__ __launch_bounds__(256) void scan_partial(const int* __restrict__ cnt, int* __restrict__ partial)
{
    __shared__ int s[256];
    int b = blockIdx.x;
    int gi = b * 512 + threadIdx.x;
    int v = 0;
    if (gi < NN) v += cnt[gi];
    if (gi + 256 < NN) v += cnt[gi + 256];
    s[threadIdx.x] = v;
    __syncthreads();
    for (int off = 128; off > 0; off >>= 1) {
        if (threadIdx.x < off) s[threadIdx.x] += s[threadIdx.x + off];
        __syncthreads();
    }
    if (threadIdx.x == 0) partial[b] = s[0];
}

__global__ __launch_bounds__(256) void scan_top(int* __restrict__ partial, int nb)
{
    __shared__ int s[256];
    int tid = threadIdx.x;
    s[tid] = (tid < nb) ? partial[tid] : 0;
    __syncthreads();
    for (int off = 1; off < 256; off <<= 1) {
        int t = (tid >= off) ? s[tid - off] : 0;
        __syncthreads();
        s[tid] += t;
        __syncthreads();
    }
    if (tid < nb) partial[tid] = (tid == 0) ? 0 : s[tid - 1];
}

__global__ __launch_bounds__(256) void scan_final(
    const int* __restrict__ cnt, const int* __restrict__ partial, int* __restrict__ row_ptr)
{
    __shared__ int s[512];
    int b = blockIdx.x;
    int tid = threadIdx.x;
    int g0 = b * 512 + tid, g1 = b * 512 + tid + 256;
    s[tid]       = (g0 < NN) ? cnt[g0] : 0;
    s[tid + 256] = (g1 < NN) ? cnt[g1] : 0;
    __syncthreads();
#pragma unroll
    for (int d = 0; d < 9; ++d) {
        int stride = 1 << d, n = 256 >> d;
        if (tid < n) s[(2 * tid + 2) * stride - 1] += s[(2 * tid + 1) * stride - 1];
        __syncthreads();
    }
    if (tid == 0) s[511] = 0;
    __syncthreads();
#pragma unroll
    for (int d = 8; d >= 0; --d) {
        int stride = 1 << d, n = 256 >> d;
        if (tid < n) {
            int i1 = (2 * tid + 1) * stride - 1, i2 = (2 * tid + 2) * stride - 1;
            int t = s[i1];
            s[i1] = s[i2];
            s[i2] += t;
        }
        __syncthreads();
    }
    int off = partial[b];
    if (g0 < NN) row_ptr[g0] = s[tid] + off;
    if (g1 < NN) row_ptr[g1] = s[tid + 256] + off;
}

__global__ __launch_bounds__(256) void cursor_init(const int* __restrict__ row_ptr, int* __restrict__ cur)
{
    int i = blockIdx.x * 256 + threadIdx.x;
    if (i < NN) cur[i] = row_ptr[i];
    if (i == 0) ((int*)row_ptr)[NN] = ETOT;
}

__global__ __launch_bounds__(256) void csr_fill(
    const int* __restrict__ ei, int* __restrict__ cur, int* __restrict__ col_src)
{
    int e = blockIdx.x * 256 + threadIdx.x;
    if (e >= ETOT) return;
    int d = edge_dst(ei, e);
    int pos = atomicAdd(&cur[d], 1);
    col_src[pos] = edge_src(ei, e);
}

// ================= per-layer weight precomputes =================
__global__ __launch_bounds__(256) void att_vec_kernel(
    const float* __restrict__ W, const float* __restrict__ attS,
    const float* __restrict__ attD, float* __restrict__ vs, float* __restrict__ vd)
{
    int tid = threadIdx.x;           // tid = k*4+h
    int k = tid >> 2, h = tid & 3;
    const float* wr = W + (size_t)k * 256 + h * 64;
    const float* as = attS + h * 64;
    const float* ad = attD + h * 64;
    float ss = 0.f, sd = 0.f;
#pragma unroll
    for (int j = 0; j < 64; ++j) {
        float wv = wr[j];
        ss += wv * as[j];
        sd += wv * ad[j];
    }
    vs[tid] = ss;
    vd[tid] = sd;
}

__global__ __launch_bounds__(256) void permW_kernel(const float* __restrict__ W, float* __restrict__ B2)
{
    int i = blockIdx.x * 256 + threadIdx.x;   // i = r*64+j, r = h*64+k
    if (i >= 256 * 64) return;
    int r = i >> 6, j = i & 63;
    int h = r >> 6, k = r & 63;
    B2[i] = W[(size_t)k * 256 + h * 64 + j];
}

// ================= attention scores directly from x =================
__global__ __launch_bounds__(256) void scores_x_kernel(
    const float* __restrict__ x, const float* __restrict__ vs,
    const float* __restrict__ vd, float4* __restrict__ a4s, float4* __restrict__ a4d)
{
    __shared__ float4 svs[64], svd[64];
    int tid = threadIdx.x;
    if (tid < 64) {
        svs[tid] = ((const float4*)vs)[tid];
        svd[tid] = ((const float4*)vd)[tid];
    }
    __syncthreads();
    int n = blockIdx.x * 256 + tid;
    if (n >= NN) return;
    const float4* xp = (const float4*)(x + (size_t)n * 64);
    float4 as = {0.f, 0.f, 0.f, 0.f}, ad = {0.f, 0.f, 0.f, 0.f};
#pragma unroll
    for (int i = 0; i < 16; ++i) {
        float4 xv = xp[i];
        float4 s0 = svs[i * 4 + 0], s1 = svs[i * 4 + 1], s2 = svs[i * 4 + 2], s3 = svs[i * 4 + 3];
        float4 d0 = svd[i * 4 + 0], d1 = svd[i * 4 + 1], d2 = svd[i * 4 + 2], d3 = svd[i * 4 + 3];
        as.x += xv.x * s0.x + xv.y * s1.x + xv.z * s2.x + xv.w * s3.x;
        as.y += xv.x * s0.y + xv.y * s1.y + xv.z * s2.y + xv.w * s3.y;
        as.z += xv.x * s0.z + xv.y * s1.z + xv.z * s2.z + xv.w * s3.z;
        as.w += xv.x * s0.w + xv.y * s1.w + xv.z * s2.w + xv.w * s3.w;
        ad.x += xv.x * d0.x + xv.y * d1.x + xv.z * d2.x + xv.w * d3.x;
        ad.y += xv.x * d0.y + xv.y * d1.y + xv.z * d2.y + xv.w * d3.y;
        ad.z += xv.x * d0.z + xv.y * d1.z + xv.z * d2.z + xv.w * d3.z;
        ad.w += xv.x * d0.w + xv.y * d1.w + xv.z * d2.w + xv.w * d3.w;
    }
    a4s[n] = as;
    a4d[n] = ad;
}

// ================= softmax per CSR row (4-way unrolled gathers) =================
__global__ __launch_bounds__(256) void row_softmax(
    const int* __restrict__ row_ptr, const int* __restrict__ col_src,
    const float4* __restrict__ a4s, const float4* __restrict__ a4d,
    float4* __restrict__ w, float4* __restrict__ inv)
{
    int d = blockIdx.x * 256 + threadIdx.x;
    if (d >= NN) return;
    int rs = row_ptr[d], re = row_ptr[d + 1];
    float4 ad = a4d[d];
    float mx = -1e30f, my = -1e30f, mz = -1e30f, mw = -1e30f;

    int e = rs;
    for (; e + 4 <= re; e += 4) {
        int s0 = col_src[e + 0], s1 = col_src[e + 1];
        int s2 = col_src[e + 2], s3 = col_src[e + 3];
        float4 v0 = a4s[s0], v1 = a4s[s1], v2 = a4s[s2], v3 = a4s[s3];
        float4 al0, al1, al2, al3;
        al0.x = lrelu(v0.x + ad.x); al0.y = lrelu(v0.y + ad.y); al0.z = lrelu(v0.z + ad.z); al0.w = lrelu(v0.w + ad.w);
        al1.x = lrelu(v1.x + ad.x); al1.y = lrelu(v1.y + ad.y); al1.z = lrelu(v1.z + ad.z); al1.w = lrelu(v1.w + ad.w);
        al2.x = lrelu(v2.x + ad.x); al2.y = lrelu(v2.y + ad.y); al2.z = lrelu(v2.z + ad.z); al2.w = lrelu(v2.w + ad.w);
        al3.x = lrelu(v3.x + ad.x); al3.y = lrelu(v3.y + ad.y); al3.z = lrelu(v3.z + ad.z); al3.w = lrelu(v3.w + ad.w);
        w[e + 0] = al0; w[e + 1] = al1; w[e + 2] = al2; w[e + 3] = al3;
        mx = fmaxf(fmaxf(fmaxf(mx, al0.x), fmaxf(al1.x, al2.x)), al3.x);
        my = fmaxf(fmaxf(fmaxf(my, al0.y), fmaxf(al1.y, al2.y)), al3.y);
        mz = fmaxf(fmaxf(fmaxf(mz, al0.z), fmaxf(al1.z, al2.z)), al3.z);
        mw = fmaxf(fmaxf(fmaxf(mw, al0.w), fmaxf(al1.w, al2.w)), al3.w);
    }
    for (; e < re; ++e) {
        int s = col_src[e];
        float4 v = a4s[s];
        float4 al;
        al.x = lrelu(v.x + ad.x); al.y = lrelu(v.y + ad.y);
        al.z = lrelu(v.z + ad.z); al.w = lrelu(v.w + ad.w);
        w[e] = al;
        mx = fmaxf(mx, al.x); my = fmaxf(my, al.y);
        mz = fmaxf(mz, al.z); mw = fmaxf(mw, al.w);
    }

    float sx = 0.f, sy = 0.f, sz = 0.f, sw = 0.f;
    e = rs;
    for (; e + 2 <= re; e += 2) {
        float4 a0 = w[e], a1 = w[e + 1];
        a0.x = expf(a0.x - mx); a0.y = expf(a0.y - my); a0.z = expf(a0.z - mz); a0.w = expf(a0.w - mw);
        a1.x = expf(a1.x - mx); a1.y = expf(a1.y - my); a1.z = expf(a1.z - mz); a1.w = expf(a1.w - mw);
        w[e] = a0; w[e + 1] = a1;
        sx += a0.x + a1.x; sy += a0.y + a1.y; sz += a0.z + a1.z; sw += a0.w + a1.w;
    }
    for (; e < re; ++e) {
        float4 a0 = w[e];
        a0.x = expf(a0.x - mx); a0.y = expf(a0.y - my);
        a0.z = expf(a0.z - mz); a0.w = expf(a0.w - mw);
        w[e] = a0;
        sx += a0.x; sy += a0.y; sz += a0.z; sw += a0.w;
    }
    float4 iv;
    iv.x = 0.25f / sx; iv.y = 0.25f / sy; iv.z = 0.25f / sz; iv.w = 0.25f / sw;
    inv[d] = iv;
}

// ================= gather aggregation in x-space (wave per dst, 4-way unrolled) =================
__global__ __launch_bounds__(256) void gather_agg_x(
    const int* __restrict__ row_ptr, const int* __restrict__ col_src,
    const float4* __restrict__ w, const float4* __restrict__ inv,
    const float* __restrict__ x, float* __restrict__ agg)
{
    int d = (blockIdx.x * 256 + threadIdx.x) >> 6;
    int lane = threadIdx.x & 63;
    if (d >= NN) return;
    int rs = row_ptr[d], re = row_ptr[d + 1];
    float a0 = 0.f, a1 = 0.f, a2 = 0.f, a3 = 0.f;

    int e = rs;
    for (; e + 4 <= re; e += 4) {
        int s0 = col_src[e + 0], s1 = col_src[e + 1];
        int s2 = col_src[e + 2], s3 = col_src[e + 3];
        float4 w0 = w[e + 0], w1 = w[e + 1], w2 = w[e + 2], w3 = w[e + 3];
        float x0 = x[(size_t)s0 * 64 + lane];
        float x1 = x[(size_t)s1 * 64 + lane];
        float x2 = x[(size_t)s2 * 64 + lane];
        float x3 = x[(size_t)s3 * 64 + lane];
        a0 += w0.x * x0 + w1.x * x1 + w2.x * x2 + w3.x * x3;
        a1 += w0.y * x0 + w1.y * x1 + w2.y * x2 + w3.y * x3;
        a2 += w0.z * x0 + w1.z * x1 + w2.z * x2 + w3.z * x3;
        a3 += w0.w * x0 + w1.w * x1 + w2.w * x2 + w3.w * x3;
    }
    for (; e < re; ++e) {
        float4 pv = w[e];
        int s = col_src[e];
        float xv = x[(size_t)s * 64 + lane];
        a0 += pv.x * xv; a1 += pv.y * xv; a2 += pv.z * xv; a3 += pv.w * xv;
    }
    float4 iv = inv[d];
    float* op = agg + (size_t)d * 256;
    op[lane]       = a0 * iv.x;
    op[64 + lane]  = a1 * iv.y;
    op[128 + lane] = a2 * iv.z;
    op[192 + lane] = a3 * iv.w;
}

// ---------------- host-side GAT layer ----------------
static void gat_layer(float* x /* in/out [N,64] */, const float* W, const float* attS,
                      const float* attD, const float* b, const int* row_ptr, const int* col_src,
                      float* agg, float4* a4s, float4* a4d, float4* inv, float4* w,
                      float* vs, float* vd, float* B2, hipStream_t stream)
{
    att_vec_kernel<<<1, 256, 0, stream>>>(W, attS, attD, vs, vd);
    permW_kernel<<<64, 256, 0, stream>>>(W, B2);
    scores_x_kernel<<<(NN + 255) / 256, 256, 0, stream>>>(x, vs, vd, a4s, a4d);
    row_softmax<<<(NN + 255) / 256, 256, 0, stream>>>(row_ptr, col_src, a4s, a4d, w, inv);
    gather_agg_x<<<(NN * 64 + 255) / 256, 256, 0, stream>>>(row_ptr, col_src, w, inv, x, agg);
    // x_out = relu(agg @ B2 + b)   (0.25 folded into inv)
    gemm_kernel<<<(NN + 63) / 64, 256, 0, stream>>>(agg, B2, b, x, NN, 256, 64, 1);
}

extern "C" void kernel_launch(void* const* d_in, const int* in_sizes, int n_in,
                              void* d_out, int out_size, void* d_ws, size_t ws_size,
                              hipStream_t stream)
{
    const float* obs     = (const float*)d_in[0];
    const int*   ei      = (const int*)d_in[1];
    const float* enc_w1  = (const float*)d_in[2];
    const float* enc_b1  = (const float*)d_in[3];
    const float* enc_w2  = (const float*)d_in[4];
    const float* enc_b2  = (const float*)d_in[5];
    const float* gat1_w  = (const float*)d_in[6];
    const float* gat1_as = (const float*)d_in[7];
    const float* gat1_ad = (const float*)d_in[8];
    const float* gat1_b  = (const float*)d_in[9];
    const float* gat2_w  = (const float*)d_in[10];
    const float* gat2_as = (const float*)d_in[11];
    const float* gat2_ad = (const float*)d_in[12];
    const float* gat2_b  = (const float*)d_in[13];
    const float* dec_w1  = (const float*)d_in[14];
    const float* dec_b1  = (const float*)d_in[15];
    const float* dec_w2  = (const float*)d_in[16];
    const float* dec_b2  = (const float*)d_in[17];

    float* ws = (float*)d_ws;
    float* bufA    = ws;                                   // [N,64]
    float* bufB    = bufA + (size_t)NN * 64;               // [N,64]  (x)
    float* agg     = bufB + (size_t)NN * 64;               // [N,256]
    float4* a4s    = (float4*)(agg + (size_t)NN * 256);    // [N]
    float4* a4d    = a4s + NN;                             // [N]
    float4* inv    = a4d + NN;                             // [N]
    float4* w      = inv + NN;                             // [ETOT]
    int* row_ptr   = (int*)(w + (size_t)ETOT);             // [N+1] (+pad)
    int* cnt       = row_ptr + NN + 4;                     // [N]
    int* cur       = cnt + NN;                             // [N]
    int* col_src   = cur + NN;                             // [ETOT]
    int* partial   = col_src + ETOT;                       // [256]
    float* vs      = (float*)(partial + 256);              // [256]
    float* vd      = vs + 256;                             // [256]
    float* B2      = vd + 256;                             // [256*64]

    const int NB = (NN + 511) / 512;
    const int GB = (NN + 63) / 64;

    // ---- CSR build (once, reused by both GAT layers) ----
    hipMemsetAsync(cnt, 0, (size_t)NN * sizeof(int), stream);
    csr_count<<<(ETOT + 255) / 256, 256, 0, stream>>>(ei, cnt);
    scan_partial<<<NB, 256, 0, stream>>>(cnt, partial);
    scan_top<<<1, 256, 0, stream>>>(partial, NB);
    scan_final<<<NB, 256, 0, stream>>>(cnt, partial, row_ptr);
    cursor_init<<<(NN + 255) / 256, 256, 0, stream>>>(row_ptr, cur);
    csr_fill<<<(ETOT + 255) / 256, 256, 0, stream>>>(ei, cur, col_src);

    // ---- encoder ----
    gemm_kernel<<<GB, 256, 0, stream>>>(obs, enc_w1, enc_b1, bufA, NN, 128, 64, 1);
    gemm_kernel<<<GB, 256, 0, stream>>>(bufA, enc_w2, enc_b2, bufB, NN, 64, 64, 0);

    // ---- GAT layers (x lives in bufB) ----
    gat_layer(bufB, gat1_w, gat1_as, gat1_ad, gat1_b, row_ptr, col_src, agg, a4s, a4d, inv, w, vs, vd, B2, stream);
    gat_layer(bufB, gat2_w, gat2_as, gat2_ad, gat2_b, row_ptr, col_src, agg, a4s, a4d, inv, w, vs, vd, B2, stream);

    // ---- decoder ----
    gemm_kernel<<<GB, 256, 0, stream>>>(bufB, dec_w1, dec_b1, bufA, NN, 64, 64, 1);
    gemm_kernel<<<GB, 256, 0, stream>>>(bufA, dec_w2, dec_b2, (float*)d_out, NN, 64, 32, 0);
}

// Round 11
// 483.851 us; speedup vs baseline: 1.4001x; 1.0425x over previous
//
#include <hip/hip_runtime.h>
#include <math.h>

#define NN 100000
#define EE 800000
#define ETOT (EE + NN)
// HID=64, HEADS=4, OBS=128, ACT=32

// ---------------- GEMM: C[M,Nc] = A[M,K] @ B[K,Nc] (+bias, optional relu) ----------------
// BM=64, BN=64, BK=16, 256 threads, 4x4 micro-tile (R9: ~6 waves/SIMD, conflict-free LDS).
__global__ __launch_bounds__(256) void gemm_kernel(
    const float* __restrict__ A, const float* __restrict__ B,
    const float* __restrict__ bias, float* __restrict__ C,
    int M, int K, int Nc, int doRelu)
{
    __shared__ __align__(16) float sA[16 * 68];  // [k][row 0..63]
    __shared__ __align__(16) float sB[16 * 68];  // [k][col 0..63]

    const int bm = blockIdx.x * 64;
    const int tid = threadIdx.x;
    const int ty = tid >> 4;   // 0..15 -> rows ty*4+i
    const int tx = tid & 15;   // 0..15 -> cols tx*4+j

    float acc[4][4] = {};

    for (int k0 = 0; k0 < K; k0 += 16) {
        {
            int r  = tid >> 2;
            int c4 = tid & 3;
            int gr = bm + r;
            float4 v = {0.f, 0.f, 0.f, 0.f};
            if (gr < M) v = *(const float4*)&A[(size_t)gr * K + k0 + c4 * 4];
            sA[(c4 * 4 + 0) * 68 + r] = v.x;
            sA[(c4 * 4 + 1) * 68 + r] = v.y;
            sA[(c4 * 4 + 2) * 68 + r] = v.z;
            sA[(c4 * 4 + 3) * 68 + r] = v.w;
        }
        {
            int row = tid >> 4;
            int c4  = (tid & 15) * 4;
            float4 v = {0.f, 0.f, 0.f, 0.f};
            if (c4 < Nc) v = *(const float4*)&B[(size_t)(k0 + row) * Nc + c4];
            *(float4*)&sB[row * 68 + c4] = v;
        }
        __syncthreads();
#pragma unroll
        for (int k = 0; k < 16; ++k) {
            float4 a0 = *(const float4*)&sA[k * 68 + ty * 4];
            float4 b0 = *(const float4*)&sB[k * 68 + tx * 4];
            float a[4] = {a0.x, a0.y, a0.z, a0.w};
            float b[4] = {b0.x, b0.y, b0.z, b0.w};
#pragma unroll
            for (int i = 0; i < 4; ++i)
#pragma unroll
                for (int j = 0; j < 4; ++j)
                    acc[i][j] = fmaf(a[i], b[j], acc[i][j]);
        }
        __syncthreads();
    }

    const int gc = tx * 4;
    float bv[4] = {0.f, 0.f, 0.f, 0.f};
    if (bias && gc < Nc) {
        bv[0] = bias[gc + 0]; bv[1] = bias[gc + 1];
        bv[2] = bias[gc + 2]; bv[3] = bias[gc + 3];
    }
    if (gc < Nc) {
#pragma unroll
        for (int i = 0; i < 4; ++i) {
            int gr = bm + ty * 4 + i;
            if (gr >= M) continue;
            float4 v;
            v.x = acc[i][0] + bv[0];
            v.y = acc[i][1] + bv[1];
            v.z = acc[i][2] + bv[2];
            v.w = acc[i][3] + bv[3];
            if (doRelu) {
                v.x = fmaxf(v.x, 0.f); v.y = fmaxf(v.y, 0.f);
                v.z = fmaxf(v.z, 0.f); v.w = fmaxf(v.w, 0.f);
            }
            *(float4*)&C[(size_t)gr * Nc + gc] = v;
        }
    }
}

__device__ __forceinline__ float lrelu(float x) { return x > 0.f ? x : 0.2f * x; }
__device__ __forceinline__ int edge_src(const int* ei, int e) { return e < EE ? ei[e] : e - EE; }
__device__ __forceinline__ int edge_dst(const int* ei, int e) { return e < EE ? ei[EE + e] : e - EE; }

// ================= CSR build =================
__global__ __launch_bounds__(256) void csr_count(const int* __restrict__ ei, int* __restrict__ cnt)
{
    int e = blockIdx.x * 256 + threadIdx.x;
    if (e >= ETOT) return;
    atomicAdd(&cnt[edge_dst(ei, e)], 1);
}

__global__ __launch_bounds__(256) void scan_partial(const int* __restrict__ cnt, int* __restrict__ partial)
{
    __shared__ int s[256];
    int b = blockIdx.x;
    int gi = b * 512 + threadIdx.x;
    int v = 0;
    if (gi < NN) v += cnt[gi];
    if (gi + 256 < NN) v += cnt[gi + 256];
    s[threadIdx.x] = v;
    __syncthreads();
    for (int off = 128; off > 0; off >>= 1) {
        if (threadIdx.x < off) s[threadIdx.x] += s[threadIdx.x + off];
        __syncthreads();
    }
    if (threadIdx.x == 0) partial[b] = s[0];
}

__global__ __launch_bounds__(256) void scan_top(int* __restrict__ partial, int nb)
{
    __shared__ int s[256];
    int tid = threadIdx.x;
    s[tid] = (tid < nb) ? partial[tid] : 0;
    __syncthreads();
    for (int off = 1; off < 256; off <<= 1) {
        int t = (tid >= off) ? s[tid - off] : 0;
        __syncthreads();
        s[tid] += t;
        __syncthreads();
    }
    if (tid < nb) partial[tid] = (tid == 0) ? 0 : s[tid - 1];
}

__global__ __launch_bounds__(256) void scan_final(
    const int* __restrict__ cnt, const int* __restrict__ partial, int* __restrict__ row_ptr)
{
    __shared__ int s[512];
    int b = blockIdx.x;
    int tid = threadIdx.x;
    int g0 = b * 512 + tid, g1 = b * 512 + tid + 256;
    s[tid]       = (g0 < NN) ? cnt[g0] : 0;
    s[tid + 256] = (g1 < NN) ? cnt[g1] : 0;
    __syncthreads();
#pragma unroll
    for (int d = 0; d < 9; ++d) {
        int stride = 1 << d, n = 256 >> d;
        if (tid < n) s[(2 * tid + 2) * stride - 1] += s[(2 * tid + 1) * stride - 1];
        __syncthreads();
    }
    if (tid == 0) s[511] = 0;
    __syncthreads();
#pragma unroll
    for (int d = 8; d >= 0; --d) {
        int stride = 1 << d, n = 256 >> d;
        if (tid < n) {
            int i1 = (2 * tid + 1) * stride - 1, i2 = (2 * tid + 2) * stride - 1;
            int t = s[i1];
            s[i1] = s[i2];
            s[i2] += t;
        }
        __syncthreads();
    }
    int off = partial[b];
    if (g0 < NN) row_ptr[g0] = s[tid] + off;
    if (g1 < NN) row_ptr[g1] = s[tid + 256] + off;
}

__global__ __launch_bounds__(256) void cursor_init(const int* __restrict__ row_ptr, int* __restrict__ cur)
{
    int i = blockIdx.x * 256 + threadIdx.x;
    if (i < NN) cur[i] = row_ptr[i];
    if (i == 0) ((int*)row_ptr)[NN] = ETOT;
}

__global__ __launch_bounds__(256) void csr_fill(
    const int* __restrict__ ei, int* __restrict__ cur, int* __restrict__ col_src)
{
    int e = blockIdx.x * 256 + threadIdx.x;
    if (e >= ETOT) return;
    int d = edge_dst(ei, e);
    int pos = atomicAdd(&cur[d], 1);
    col_src[pos] = edge_src(ei, e);
}

// ================= per-layer weight precomputes =================
__global__ __launch_bounds__(256) void att_vec_kernel(
    const float* __restrict__ W, const float* __restrict__ attS,
    const float* __restrict__ attD, float* __restrict__ vs, float* __restrict__ vd)
{
    int tid = threadIdx.x;           // tid = k*4+h
    int k = tid >> 2, h = tid & 3;
    const float* wr = W + (size_t)k * 256 + h * 64;
    const float* as = attS + h * 64;
    const float* ad = attD + h * 64;
    float ss = 0.f, sd = 0.f;
#pragma unroll
    for (int j = 0; j < 64; ++j) {
        float wv = wr[j];
        ss += wv * as[j];
        sd += wv * ad[j];
    }
    vs[tid] = ss;
    vd[tid] = sd;
}

__global__ __launch_bounds__(256) void permW_kernel(const float* __restrict__ W, float* __restrict__ B2)
{
    int i = blockIdx.x * 256 + threadIdx.x;   // i = r*64+j, r = h*64+k
    if (i >= 256 * 64) return;
    int r = i >> 6, j = i & 63;
    int h = r >> 6, k = r & 63;
    B2[i] = W[(size_t)k * 256 + h * 64 + j];
}

// ================= attention scores directly from x =================
__global__ __launch_bounds__(256) void scores_x_kernel(
    const float* __restrict__ x, const float* __restrict__ vs,
    const float* __restrict__ vd, float4* __restrict__ a4s, float4* __restrict__ a4d)
{
    __shared__ float4 svs[64], svd[64];
    int tid = threadIdx.x;
    if (tid < 64) {
        svs[tid] = ((const float4*)vs)[tid];
        svd[tid] = ((const float4*)vd)[tid];
    }
    __syncthreads();
    int n = blockIdx.x * 256 + tid;
    if (n >= NN) return;
    const float4* xp = (const float4*)(x + (size_t)n * 64);
    float4 as = {0.f, 0.f, 0.f, 0.f}, ad = {0.f, 0.f, 0.f, 0.f};
#pragma unroll
    for (int i = 0; i < 16; ++i) {
        float4 xv = xp[i];
        float4 s0 = svs[i * 4 + 0], s1 = svs[i * 4 + 1], s2 = svs[i * 4 + 2], s3 = svs[i * 4 + 3];
        float4 d0 = svd[i * 4 + 0], d1 = svd[i * 4 + 1], d2 = svd[i * 4 + 2], d3 = svd[i * 4 + 3];
        as.x += xv.x * s0.x + xv.y * s1.x + xv.z * s2.x + xv.w * s3.x;
        as.y += xv.x * s0.y + xv.y * s1.y + xv.z * s2.y + xv.w * s3.y;
        as.z += xv.x * s0.z + xv.y * s1.z + xv.z * s2.z + xv.w * s3.z;
        as.w += xv.x * s0.w + xv.y * s1.w + xv.z * s2.w + xv.w * s3.w;
        ad.x += xv.x * d0.x + xv.y * d1.x + xv.z * d2.x + xv.w * d3.x;
        ad.y += xv.x * d0.y + xv.y * d1.y + xv.z * d2.y + xv.w * d3.y;
        ad.z += xv.x * d0.z + xv.y * d1.z + xv.z * d2.z + xv.w * d3.z;
        ad.w += xv.x * d0.w + xv.y * d1.w + xv.z * d2.w + xv.w * d3.w;
    }
    a4s[n] = as;
    a4d[n] = ad;
}

// ================= softmax per CSR row — single pass, no max subtraction =================
// p/s is shift-invariant: exp(a-m)/sum(exp(a-m)) == exp(a)/sum(exp(a)); alpha is bounded
// (|alpha| << 88) so exp cannot overflow in fp32. One gather pass, store p, compute inv.
__global__ __launch_bounds__(256) void row_softmax(
    const int* __restrict__ row_ptr, const int* __restrict__ col_src,
    const float4* __restrict__ a4s, const float4* __restrict__ a4d,
    float4* __restrict__ w, float4* __restrict__ inv)
{
    int d = blockIdx.x * 256 + threadIdx.x;
    if (d >= NN) return;
    int rs = row_ptr[d], re = row_ptr[d + 1];
    float4 ad = a4d[d];
    float sx = 0.f, sy = 0.f, sz = 0.f, sw = 0.f;

    int e = rs;
    for (; e + 4 <= re; e += 4) {
        int s0 = col_src[e + 0], s1 = col_src[e + 1];
        int s2 = col_src[e + 2], s3 = col_src[e + 3];
        float4 v0 = a4s[s0], v1 = a4s[s1], v2 = a4s[s2], v3 = a4s[s3];
        float4 p0, p1, p2, p3;
        p0.x = expf(lrelu(v0.x + ad.x)); p0.y = expf(lrelu(v0.y + ad.y));
        p0.z = expf(lrelu(v0.z + ad.z)); p0.w = expf(lrelu(v0.w + ad.w));
        p1.x = expf(lrelu(v1.x + ad.x)); p1.y = expf(lrelu(v1.y + ad.y));
        p1.z = expf(lrelu(v1.z + ad.z)); p1.w = expf(lrelu(v1.w + ad.w));
        p2.x = expf(lrelu(v2.x + ad.x)); p2.y = expf(lrelu(v2.y + ad.y));
        p2.z = expf(lrelu(v2.z + ad.z)); p2.w = expf(lrelu(v2.w + ad.w));
        p3.x = expf(lrelu(v3.x + ad.x)); p3.y = expf(lrelu(v3.y + ad.y));
        p3.z = expf(lrelu(v3.z + ad.z)); p3.w = expf(lrelu(v3.w + ad.w));
        w[e + 0] = p0; w[e + 1] = p1; w[e + 2] = p2; w[e + 3] = p3;
        sx += p0.x + p1.x + p2.x + p3.x;
        sy += p0.y + p1.y + p2.y + p3.y;
        sz += p0.z + p1.z + p2.z + p3.z;
        sw += p0.w + p1.w + p2.w + p3.w;
    }
    for (; e < re; ++e) {
        int s = col_src[e];
        float4 v = a4s[s];
        float4 p;
        p.x = expf(lrelu(v.x + ad.x)); p.y = expf(lrelu(v.y + ad.y));
        p.z = expf(lrelu(v.z + ad.z)); p.w = expf(lrelu(v.w + ad.w));
        w[e] = p;
        sx += p.x; sy += p.y; sz += p.z; sw += p.w;
    }
    float4 iv;
    iv.x = 0.25f / sx; iv.y = 0.25f / sy; iv.z = 0.25f / sz; iv.w = 0.25f / sw;
    inv[d] = iv;
}

// ================= gather aggregation in x-space (wave per dst, 8/4/2/1 ladder) =================
__global__ __launch_bounds__(256) void gather_agg_x(
    const int* __restrict__ row_ptr, const int* __restrict__ col_src,
    const float4* __restrict__ w, const float4* __restrict__ inv,
    const float* __restrict__ x, float* __restrict__ agg)
{
    int d = (blockIdx.x * 256 + threadIdx.x) >> 6;
    int lane = threadIdx.x & 63;
    if (d >= NN) return;
    int rs = row_ptr[d], re = row_ptr[d + 1];
    float a0 = 0.f, a1 = 0.f, a2 = 0.f, a3 = 0.f;

    int e = rs;
    for (; e + 8 <= re; e += 8) {
        int s[8];
#pragma unroll
        for (int u = 0; u < 8; ++u) s[u] = col_src[e + u];
        float4 wv[8];
#pragma unroll
        for (int u = 0; u < 8; ++u) wv[u] = w[e + u];
        float xv[8];
#pragma unroll
        for (int u = 0; u < 8; ++u) xv[u] = x[(size_t)s[u] * 64 + lane];
#pragma unroll
        for (int u = 0; u < 8; ++u) {
            a0 = fmaf(wv[u].x, xv[u], a0);
            a1 = fmaf(wv[u].y, xv[u], a1);
            a2 = fmaf(wv[u].z, xv[u], a2);
            a3 = fmaf(wv[u].w, xv[u], a3);
        }
    }
    if (e + 4 <= re) {
        int s[4];
#pragma unroll
        for (int u = 0; u < 4; ++u) s[u] = col_src[e + u];
        float4 wv[4];
#pragma unroll
        for (int u = 0; u < 4; ++u) wv[u] = w[e + u];
        float xv[4];
#pragma unroll
        for (int u = 0; u < 4; ++u) xv[u] = x[(size_t)s[u] * 64 + lane];
#pragma unroll
        for (int u = 0; u < 4; ++u) {
            a0 = fmaf(wv[u].x, xv[u], a0);
            a1 = fmaf(wv[u].y, xv[u], a1);
            a2 = fmaf(wv[u].z, xv[u], a2);
            a3 = fmaf(wv[u].w, xv[u], a3);
        }
        e += 4;
    }
    if (e + 2 <= re) {
        int s0 = col_src[e], s1 = col_src[e + 1];
        float4 w0 = w[e], w1 = w[e + 1];
        float x0 = x[(size_t)s0 * 64 + lane];
        float x1 = x[(size_t)s1 * 64 + lane];
        a0 += w0.x * x0 + w1.x * x1;
        a1 += w0.y * x0 + w1.y * x1;
        a2 += w0.z * x0 + w1.z * x1;
        a3 += w0.w * x0 + w1.w * x1;
        e += 2;
    }
    if (e < re) {
        int s0 = col_src[e];
        float4 w0 = w[e];
        float x0 = x[(size_t)s0 * 64 + lane];
        a0 = fmaf(w0.x, x0, a0);
        a1 = fmaf(w0.y, x0, a1);
        a2 = fmaf(w0.z, x0, a2);
        a3 = fmaf(w0.w, x0, a3);
    }
    float4 iv = inv[d];
    float* op = agg + (size_t)d * 256;
    op[lane]       = a0 * iv.x;
    op[64 + lane]  = a1 * iv.y;
    op[128 + lane] = a2 * iv.z;
    op[192 + lane] = a3 * iv.w;
}

// ---------------- host-side GAT layer ----------------
static void gat_layer(float* x /* in/out [N,64] */, const float* W, const float* attS,
                      const float* attD, const float* b, const int* row_ptr, const int* col_src,
                      float* agg, float4* a4s, float4* a4d, float4* inv, float4* w,
                      float* vs, float* vd, float* B2, hipStream_t stream)
{
    att_vec_kernel<<<1, 256, 0, stream>>>(W, attS, attD, vs, vd);
    permW_kernel<<<64, 256, 0, stream>>>(W, B2);
    scores_x_kernel<<<(NN + 255) / 256, 256, 0, stream>>>(x, vs, vd, a4s, a4d);
    row_softmax<<<(NN + 255) / 256, 256, 0, stream>>>(row_ptr, col_src, a4s, a4d, w, inv);
    gather_agg_x<<<(NN * 64 + 255) / 256, 256, 0, stream>>>(row_ptr, col_src, w, inv, x, agg);
    // x_out = relu(agg @ B2 + b)   (0.25 folded into inv)
    gemm_kernel<<<(NN + 63) / 64, 256, 0, stream>>>(agg, B2, b, x, NN, 256, 64, 1);
}

extern "C" void kernel_launch(void* const* d_in, const int* in_sizes, int n_in,
                              void* d_out, int out_size, void* d_ws, size_t ws_size,
                              hipStream_t stream)
{
    const float* obs     = (const float*)d_in[0];
    const int*   ei      = (const int*)d_in[1];
    const float* enc_w1  = (const float*)d_in[2];
    const float* enc_b1  = (const float*)d_in[3];
    const float* enc_w2  = (const float*)d_in[4];
    const float* enc_b2  = (const float*)d_in[5];
    const float* gat1_w  = (const float*)d_in[6];
    const float* gat1_as = (const float*)d_in[7];
    const float* gat1_ad = (const float*)d_in[8];
    const float* gat1_b  = (const float*)d_in[9];
    const float* gat2_w  = (const float*)d_in[10];
    const float* gat2_as = (const float*)d_in[11];
    const float* gat2_ad = (const float*)d_in[12];
    const float* gat2_b  = (const float*)d_in[13];
    const float* dec_w1  = (const float*)d_in[14];
    const float* dec_b1  = (const float*)d_in[15];
    const float* dec_w2  = (const float*)d_in[16];
    const float* dec_b2  = (const float*)d_in[17];

    float* ws = (float*)d_ws;
    float* bufA    = ws;                                   // [N,64]
    float* bufB    = bufA + (size_t)NN * 64;               // [N,64]  (x)
    float* agg     = bufB + (size_t)NN * 64;               // [N,256]
    float4* a4s    = (float4*)(agg + (size_t)NN * 256);    // [N]
    float4* a4d    = a4s + NN;                             // [N]
    float4* inv    = a4d + NN;                             // [N]
    float4* w      = inv + NN;                             // [ETOT]
    int* row_ptr   = (int*)(w + (size_t)ETOT);             // [N+1] (+pad)
    int* cnt       = row_ptr + NN + 4;                     // [N]
    int* cur       = cnt + NN;                             // [N]
    int* col_src   = cur + NN;                             // [ETOT]
    int* partial   = col_src + ETOT;                       // [256]
    float* vs      = (float*)(partial + 256);              // [256]
    float* vd      = vs + 256;                             // [256]
    float* B2      = vd + 256;                             // [256*64]

    const int NB = (NN + 511) / 512;
    const int GB = (NN + 63) / 64;

    // ---- CSR build (once, reused by both GAT layers) ----
    hipMemsetAsync(cnt, 0, (size_t)NN * sizeof(int), stream);
    csr_count<<<(ETOT + 255) / 256, 256, 0, stream>>>(ei, cnt);
    scan_partial<<<NB, 256, 0, stream>>>(cnt, partial);
    scan_top<<<1, 256, 0, stream>>>(partial, NB);
    scan_final<<<NB, 256, 0, stream>>>(cnt, partial, row_ptr);
    cursor_init<<<(NN + 255) / 256, 256, 0, stream>>>(row_ptr, cur);
    csr_fill<<<(ETOT + 255) / 256, 256, 0, stream>>>(ei, cur, col_src);

    // ---- encoder ----
    gemm_kernel<<<GB, 256, 0, stream>>>(obs, enc_w1, enc_b1, bufA, NN, 128, 64, 1);
    gemm_kernel<<<GB, 256, 0, stream>>>(bufA, enc_w2, enc_b2, bufB, NN, 64, 64, 0);

    // ---- GAT layers (x lives in bufB) ----
    gat_layer(bufB, gat1_w, gat1_as, gat1_ad, gat1_b, row_ptr, col_src, agg, a4s, a4d, inv, w, vs, vd, B2, stream);
    gat_layer(bufB, gat2_w, gat2_as, gat2_ad, gat2_b, row_ptr, col_src, agg, a4s, a4d, inv, w, vs, vd, B2, stream);

    // ---- decoder ----
    gemm_kernel<<<GB, 256, 0, stream>>>(bufB, dec_w1, dec_b1, bufA, NN, 64, 64, 1);
    gemm_kernel<<<GB, 256, 0, stream>>>(bufA, dec_w2, dec_b2, (float*)d_out, NN, 64, 32, 0);
}

// Round 12
// 456.376 us; speedup vs baseline: 1.4844x; 1.0602x over previous
//
#include <hip/hip_runtime.h>
#include <math.h>

#define NN 100000
#define EE 800000
#define ETOT (EE + NN)
#define CAP 128
// HID=64, HEADS=4, OBS=128, ACT=32

// ---------------- GEMM: C[M,Nc] = A[M,K] @ B[K,Nc] (+bias, optional relu) ----------------
// BM=64, BN=64, BK=16, 256 threads, 4x4 micro-tile (R9: ~6 waves/SIMD, conflict-free LDS).
__global__ __launch_bounds__(256) void gemm_kernel(
    const float* __restrict__ A, const float* __restrict__ B,
    const float* __restrict__ bias, float* __restrict__ C,
    int M, int K, int Nc, int doRelu)
{
    __shared__ __align__(16) float sA[16 * 68];  // [k][row 0..63]
    __shared__ __align__(16) float sB[16 * 68];  // [k][col 0..63]

    const int bm = blockIdx.x * 64;
    const int tid = threadIdx.x;
    const int ty = tid >> 4;   // 0..15 -> rows ty*4+i
    const int tx = tid & 15;   // 0..15 -> cols tx*4+j

    float acc[4][4] = {};

    for (int k0 = 0; k0 < K; k0 += 16) {
        {
            int r  = tid >> 2;
            int c4 = tid & 3;
            int gr = bm + r;
            float4 v = {0.f, 0.f, 0.f, 0.f};
            if (gr < M) v = *(const float4*)&A[(size_t)gr * K + k0 + c4 * 4];
            sA[(c4 * 4 + 0) * 68 + r] = v.x;
            sA[(c4 * 4 + 1) * 68 + r] = v.y;
            sA[(c4 * 4 + 2) * 68 + r] = v.z;
            sA[(c4 * 4 + 3) * 68 + r] = v.w;
        }
        {
            int row = tid >> 4;
            int c4  = (tid & 15) * 4;
            float4 v = {0.f, 0.f, 0.f, 0.f};
            if (c4 < Nc) v = *(const float4*)&B[(size_t)(k0 + row) * Nc + c4];
            *(float4*)&sB[row * 68 + c4] = v;
        }
        __syncthreads();
#pragma unroll
        for (int k = 0; k < 16; ++k) {
            float4 a0 = *(const float4*)&sA[k * 68 + ty * 4];
            float4 b0 = *(const float4*)&sB[k * 68 + tx * 4];
            float a[4] = {a0.x, a0.y, a0.z, a0.w};
            float b[4] = {b0.x, b0.y, b0.z, b0.w};
#pragma unroll
            for (int i = 0; i < 4; ++i)
#pragma unroll
                for (int j = 0; j < 4; ++j)
                    acc[i][j] = fmaf(a[i], b[j], acc[i][j]);
        }
        __syncthreads();
    }

    const int gc = tx * 4;
    float bv[4] = {0.f, 0.f, 0.f, 0.f};
    if (bias && gc < Nc) {
        bv[0] = bias[gc + 0]; bv[1] = bias[gc + 1];
        bv[2] = bias[gc + 2]; bv[3] = bias[gc + 3];
    }
    if (gc < Nc) {
#pragma unroll
        for (int i = 0; i < 4; ++i) {
            int gr = bm + ty * 4 + i;
            if (gr >= M) continue;
            float4 v;
            v.x = acc[i][0] + bv[0];
            v.y = acc[i][1] + bv[1];
            v.z = acc[i][2] + bv[2];
            v.w = acc[i][3] + bv[3];
            if (doRelu) {
                v.x = fmaxf(v.x, 0.f); v.y = fmaxf(v.y, 0.f);
                v.z = fmaxf(v.z, 0.f); v.w = fmaxf(v.w, 0.f);
            }
            *(float4*)&C[(size_t)gr * Nc + gc] = v;
        }
    }
}

__device__ __forceinline__ float lrelu(float x) { return x > 0.f ? x : 0.2f * x; }
__device__ __forceinline__ int edge_src(const int* ei, int e) { return e < EE ? ei[e] : e - EE; }
__device__ __forceinline__ int edge_dst(const int* ei, int e) { return e < EE ? ei[EE + e] : e - EE; }

// ================= CSR build =================
__global__ __launch_bounds__(256) void csr_count(const int* __restrict__ ei, int* __restrict__ cnt)
{
    int e = blockIdx.x * 256 + threadIdx.x;
    if (e >= ETOT) return;
    atomicAdd(&cnt[edge_dst(ei, e)], 1);
}

__global__ __launch_bounds__(256) void scan_partial(const int* __restrict__ cnt, int* __restrict__ partial)
{
    __shared__ int s[256];
    int b = blockIdx.x;
    int gi = b * 512 + threadIdx.x;
    int v = 0;
    if (gi < NN) v += cnt[gi];
    if (gi + 256 < NN) v += cnt[gi + 256];
    s[threadIdx.x] = v;
    __syncthreads();
    for (int off = 128; off > 0; off >>= 1) {
        if (threadIdx.x < off) s[threadIdx.x] += s[threadIdx.x + off];
        __syncthreads();
    }
    if (threadIdx.x == 0) partial[b] = s[0];
}

__global__ __launch_bounds__(256) void scan_top(int* __restrict__ partial, int nb)
{
    __shared__ int s[256];
    int tid = threadIdx.x;
    s[tid] = (tid < nb) ? partial[tid] : 0;
    __syncthreads();
    for (int off = 1; off < 256; off <<= 1) {
        int t = (tid >= off) ? s[tid - off] : 0;
        __syncthreads();
        s[tid] += t;
        __syncthreads();
    }
    if (tid < nb) partial[tid] = (tid == 0) ? 0 : s[tid - 1];
}

__global__ __launch_bounds__(256) void scan_final(
    const int* __restrict__ cnt, const int* __restrict__ partial, int* __restrict__ row_ptr)
{
    __shared__ int s[512];
    int b = blockIdx.x;
    int tid = threadIdx.x;
    int g0 = b * 512 + tid, g1 = b * 512 + tid + 256;
    s[tid]       = (g0 < NN) ? cnt[g0] : 0;
    s[tid + 256] = (g1 < NN) ? cnt[g1] : 0;
    __syncthreads();
#pragma unroll
    for (int d = 0; d < 9; ++d) {
        int stride = 1 << d, n = 256 >> d;
        if (tid < n) s[(2 * tid + 2) * stride - 1] += s[(2 * tid + 1) * stride - 1];
        __syncthreads();
    }
    if (tid == 0) s[511] = 0;
    __syncthreads();
#pragma unroll
    for (int d = 8; d >= 0; --d) {
        int stride = 1 << d, n = 256 >> d;
        if (tid < n) {
            int i1 = (2 * tid + 1) * stride - 1, i2 = (2 * tid + 2) * stride - 1;
            int t = s[i1];
            s[i1] = s[i2];
            s[i2] += t;
        }
        __syncthreads();
    }
    int off = partial[b];
    if (g0 < NN) row_ptr[g0] = s[tid] + off;
    if (g1 < NN) row_ptr[g1] = s[tid + 256] + off;
}

__global__ __launch_bounds__(256) void cursor_init(const int* __restrict__ row_ptr, int* __restrict__ cur)
{
    int i = blockIdx.x * 256 + threadIdx.x;
    if (i < NN) cur[i] = row_ptr[i];
    if (i == 0) ((int*)row_ptr)[NN] = ETOT;
}

__global__ __launch_bounds__(256) void csr_fill(
    const int* __restrict__ ei, int* __restrict__ cur, int* __restrict__ col_src)
{
    int e = blockIdx.x * 256 + threadIdx.x;
    if (e >= ETOT) return;
    int d = edge_dst(ei, e);
    int pos = atomicAdd(&cur[d], 1);
    col_src[pos] = edge_src(ei, e);
}

// ================= per-layer weight precomputes =================
__global__ __launch_bounds__(256) void att_vec_kernel(
    const float* __restrict__ W, const float* __restrict__ attS,
    const float* __restrict__ attD, float* __restrict__ vs, float* __restrict__ vd)
{
    int tid = threadIdx.x;           // tid = k*4+h
    int k = tid >> 2, h = tid & 3;
    const float* wr = W + (size_t)k * 256 + h * 64;
    const float* as = attS + h * 64;
    const float* ad = attD + h * 64;
    float ss = 0.f, sd = 0.f;
#pragma unroll
    for (int j = 0; j < 64; ++j) {
        float wv = wr[j];
        ss += wv * as[j];
        sd += wv * ad[j];
    }
    vs[tid] = ss;
    vd[tid] = sd;
}

__global__ __launch_bounds__(256) void permW_kernel(const float* __restrict__ W, float* __restrict__ B2)
{
    int i = blockIdx.x * 256 + threadIdx.x;   // i = r*64+j, r = h*64+k
    if (i >= 256 * 64) return;
    int r = i >> 6, j = i & 63;
    int h = r >> 6, k = r & 63;
    B2[i] = W[(size_t)k * 256 + h * 64 + j];
}

// ================= attention scores directly from x =================
__global__ __launch_bounds__(256) void scores_x_kernel(
    const float* __restrict__ x, const float* __restrict__ vs,
    const float* __restrict__ vd, float4* __restrict__ a4s, float4* __restrict__ a4d)
{
    __shared__ float4 svs[64], svd[64];
    int tid = threadIdx.x;
    if (tid < 64) {
        svs[tid] = ((const float4*)vs)[tid];
        svd[tid] = ((const float4*)vd)[tid];
    }
    __syncthreads();
    int n = blockIdx.x * 256 + tid;
    if (n >= NN) return;
    const float4* xp = (const float4*)(x + (size_t)n * 64);
    float4 as = {0.f, 0.f, 0.f, 0.f}, ad = {0.f, 0.f, 0.f, 0.f};
#pragma unroll
    for (int i = 0; i < 16; ++i) {
        float4 xv = xp[i];
        float4 s0 = svs[i * 4 + 0], s1 = svs[i * 4 + 1], s2 = svs[i * 4 + 2], s3 = svs[i * 4 + 3];
        float4 d0 = svd[i * 4 + 0], d1 = svd[i * 4 + 1], d2 = svd[i * 4 + 2], d3 = svd[i * 4 + 3];
        as.x += xv.x * s0.x + xv.y * s1.x + xv.z * s2.x + xv.w * s3.x;
        as.y += xv.x * s0.y + xv.y * s1.y + xv.z * s2.y + xv.w * s3.y;
        as.z += xv.x * s0.z + xv.y * s1.z + xv.z * s2.z + xv.w * s3.z;
        as.w += xv.x * s0.w + xv.y * s1.w + xv.z * s2.w + xv.w * s3.w;
        ad.x += xv.x * d0.x + xv.y * d1.x + xv.z * d2.x + xv.w * d3.x;
        ad.y += xv.x * d0.y + xv.y * d1.y + xv.z * d2.y + xv.w * d3.y;
        ad.z += xv.x * d0.z + xv.y * d1.z + xv.z * d2.z + xv.w * d3.z;
        ad.w += xv.x * d0.w + xv.y * d1.w + xv.z * d2.w + xv.w * d3.w;
    }
    a4s[n] = as;
    a4d[n] = ad;
}

// ================= fused softmax + gather aggregation (wave per dst) =================
// Phase A: lanes gather a4s[src] edge-parallel, p=exp(lrelu(.)), stash (p,src) in LDS,
//          shfl-reduce head sums -> inv in registers.  (shift-free softmax, validated R10)
// Phase B: feature-parallel x gather with LDS-broadcast (p,src), 4-deep unroll.
// Slow path (deg > CAP, prob ~0 for Poisson(9)): recompute p per edge wave-uniform.
__global__ __launch_bounds__(256) void gat_fused(
    const int* __restrict__ row_ptr, const int* __restrict__ col_src,
    const float4* __restrict__ a4s, const float4* __restrict__ a4d,
    const float* __restrict__ x, float* __restrict__ agg)
{
    __shared__ float4 sp[4][CAP];
    __shared__ int    ssrc[4][CAP];
    const int wslot = threadIdx.x >> 6;
    const int lane = threadIdx.x & 63;
    const int d = (blockIdx.x * 256 + threadIdx.x) >> 6;   // grid sized so d < NN always

    const int rs = row_ptr[d];
    const int deg = row_ptr[d + 1] - rs;
    const float4 ad = a4d[d];

    // ---- Phase A ----
    float px = 0.f, py = 0.f, pz = 0.f, pw = 0.f;
    for (int base = 0; base < deg; base += 64) {
        int idx = base + lane;
        float4 p = {0.f, 0.f, 0.f, 0.f};
        int s = 0;
        if (idx < deg) {
            s = col_src[rs + idx];
            float4 v = a4s[s];
            p.x = expf(lrelu(v.x + ad.x));
            p.y = expf(lrelu(v.y + ad.y));
            p.z = expf(lrelu(v.z + ad.z));
            p.w = expf(lrelu(v.w + ad.w));
        }
        if (idx < CAP) { sp[wslot][idx] = p; ssrc[wslot][idx] = s; }
        px += p.x; py += p.y; pz += p.z; pw += p.w;
    }
#pragma unroll
    for (int off = 32; off > 0; off >>= 1) {
        px += __shfl_xor(px, off, 64);
        py += __shfl_xor(py, off, 64);
        pz += __shfl_xor(pz, off, 64);
        pw += __shfl_xor(pw, off, 64);
    }
    const float ivx = 0.25f / px, ivy = 0.25f / py, ivz = 0.25f / pz, ivw = 0.25f / pw;

    // ---- Phase B ----
    float a0 = 0.f, a1 = 0.f, a2 = 0.f, a3 = 0.f;
    const int lim = deg < CAP ? deg : CAP;
    int e = 0;
    for (; e + 4 <= lim; e += 4) {
        float4 p0 = sp[wslot][e + 0], p1 = sp[wslot][e + 1];
        float4 p2 = sp[wslot][e + 2], p3 = sp[wslot][e + 3];
        int s0 = ssrc[wslot][e + 0], s1 = ssrc[wslot][e + 1];
        int s2 = ssrc[wslot][e + 2], s3 = ssrc[wslot][e + 3];
        float x0 = x[(size_t)s0 * 64 + lane];
        float x1 = x[(size_t)s1 * 64 + lane];
        float x2 = x[(size_t)s2 * 64 + lane];
        float x3 = x[(size_t)s3 * 64 + lane];
        a0 += p0.x * x0 + p1.x * x1 + p2.x * x2 + p3.x * x3;
        a1 += p0.y * x0 + p1.y * x1 + p2.y * x2 + p3.y * x3;
        a2 += p0.z * x0 + p1.z * x1 + p2.z * x2 + p3.z * x3;
        a3 += p0.w * x0 + p1.w * x1 + p2.w * x2 + p3.w * x3;
    }
    for (; e < lim; ++e) {
        float4 p = sp[wslot][e];
        int s = ssrc[wslot][e];
        float xv = x[(size_t)s * 64 + lane];
        a0 = fmaf(p.x, xv, a0);
        a1 = fmaf(p.y, xv, a1);
        a2 = fmaf(p.z, xv, a2);
        a3 = fmaf(p.w, xv, a3);
    }
    for (; e < deg; ++e) {   // slow path, statistically never taken
        int s = col_src[rs + e];
        float4 v = a4s[s];
        float4 p;
        p.x = expf(lrelu(v.x + ad.x)); p.y = expf(lrelu(v.y + ad.y));
        p.z = expf(lrelu(v.z + ad.z)); p.w = expf(lrelu(v.w + ad.w));
        float xv = x[(size_t)s * 64 + lane];
        a0 = fmaf(p.x, xv, a0);
        a1 = fmaf(p.y, xv, a1);
        a2 = fmaf(p.z, xv, a2);
        a3 = fmaf(p.w, xv, a3);
    }

    float* op = agg + (size_t)d * 256;
    op[lane]       = a0 * ivx;
    op[64 + lane]  = a1 * ivy;
    op[128 + lane] = a2 * ivz;
    op[192 + lane] = a3 * ivw;
}

// ---------------- host-side GAT layer ----------------
static void gat_layer(float* x /* in/out [N,64] */, const float* W, const float* attS,
                      const float* attD, const float* b, const int* row_ptr, const int* col_src,
                      float* agg, float4* a4s, float4* a4d,
                      float* vs, float* vd, float* B2, hipStream_t stream)
{
    att_vec_kernel<<<1, 256, 0, stream>>>(W, attS, attD, vs, vd);
    permW_kernel<<<64, 256, 0, stream>>>(W, B2);
    scores_x_kernel<<<(NN + 255) / 256, 256, 0, stream>>>(x, vs, vd, a4s, a4d);
    gat_fused<<<(NN * 64) / 256, 256, 0, stream>>>(row_ptr, col_src, a4s, a4d, x, agg);
    // x_out = relu(agg @ B2 + b)   (0.25 folded into inv)
    gemm_kernel<<<(NN + 63) / 64, 256, 0, stream>>>(agg, B2, b, x, NN, 256, 64, 1);
}

extern "C" void kernel_launch(void* const* d_in, const int* in_sizes, int n_in,
                              void* d_out, int out_size, void* d_ws, size_t ws_size,
                              hipStream_t stream)
{
    const float* obs     = (const float*)d_in[0];
    const int*   ei      = (const int*)d_in[1];
    const float* enc_w1  = (const float*)d_in[2];
    const float* enc_b1  = (const float*)d_in[3];
    const float* enc_w2  = (const float*)d_in[4];
    const float* enc_b2  = (const float*)d_in[5];
    const float* gat1_w  = (const float*)d_in[6];
    const float* gat1_as = (const float*)d_in[7];
    const float* gat1_ad = (const float*)d_in[8];
    const float* gat1_b  = (const float*)d_in[9];
    const float* gat2_w  = (const float*)d_in[10];
    const float* gat2_as = (const float*)d_in[11];
    const float* gat2_ad = (const float*)d_in[12];
    const float* gat2_b  = (const float*)d_in[13];
    const float* dec_w1  = (const float*)d_in[14];
    const float* dec_b1  = (const float*)d_in[15];
    const float* dec_w2  = (const float*)d_in[16];
    const float* dec_b2  = (const float*)d_in[17];

    float* ws = (float*)d_ws;
    float* bufA    = ws;                                   // [N,64]
    float* bufB    = bufA + (size_t)NN * 64;               // [N,64]  (x)
    float* agg     = bufB + (size_t)NN * 64;               // [N,256]
    float4* a4s    = (float4*)(agg + (size_t)NN * 256);    // [N]
    float4* a4d    = a4s + NN;                             // [N]
    int* row_ptr   = (int*)(a4d + NN);                     // [N+1] (+pad)
    int* cnt       = row_ptr + NN + 4;                     // [N]
    int* cur       = cnt + NN;                             // [N]
    int* col_src   = cur + NN;                             // [ETOT]
    int* partial   = col_src + ETOT;                       // [256]
    float* vs      = (float*)(partial + 256);              // [256]
    float* vd      = vs + 256;                             // [256]
    float* B2      = vd + 256;                             // [256*64]

    const int NB = (NN + 511) / 512;
    const int GB = (NN + 63) / 64;

    // ---- CSR build (once, reused by both GAT layers) ----
    hipMemsetAsync(cnt, 0, (size_t)NN * sizeof(int), stream);
    csr_count<<<(ETOT + 255) / 256, 256, 0, stream>>>(ei, cnt);
    scan_partial<<<NB, 256, 0, stream>>>(cnt, partial);
    scan_top<<<1, 256, 0, stream>>>(partial, NB);
    scan_final<<<NB, 256, 0, stream>>>(cnt, partial, row_ptr);
    cursor_init<<<(NN + 255) / 256, 256, 0, stream>>>(row_ptr, cur);
    csr_fill<<<(ETOT + 255) / 256, 256, 0, stream>>>(ei, cur, col_src);

    // ---- encoder ----
    gemm_kernel<<<GB, 256, 0, stream>>>(obs, enc_w1, enc_b1, bufA, NN, 128, 64, 1);
    gemm_kernel<<<GB, 256, 0, stream>>>(bufA, enc_w2, enc_b2, bufB, NN, 64, 64, 0);

    // ---- GAT layers (x lives in bufB) ----
    gat_layer(bufB, gat1_w, gat1_as, gat1_ad, gat1_b, row_ptr, col_src, agg, a4s, a4d, vs, vd, B2, stream);
    gat_layer(bufB, gat2_w, gat2_as, gat2_ad, gat2_b, row_ptr, col_src, agg, a4s, a4d, vs, vd, B2, stream);

    // ---- decoder ----
    gemm_kernel<<<GB, 256, 0, stream>>>(bufB, dec_w1, dec_b1, bufA, NN, 64, 64, 1);
    gemm_kernel<<<GB, 256, 0, stream>>>(bufA, dec_w2, dec_b2, (float*)d_out, NN, 64, 32, 0);
}